// Round 1
// baseline (661.726 us; speedup 1.0000x reference)
//
#include <hip/hip_runtime.h>
#include <cstddef>

#define N_    4096
#define C_    512
#define OUT_  256
#define EPSF  1e-5f

#define NSPLIT 32          // column splits for syrk_topk (4096/128)
#define NCAND  (NSPLIT*4)  // 128 candidates per row
#define NCHK   12          // candidates re-checked in fp64
#define MAXN   12          // max stored neighbors

// ---------------------------------------------------------------------------
// Generic fp32 GEMM: Cm[M,Nc] = A[M,K] @ B[Nc,K]^T + bias[Nc]
// BM=64, BN=64, BK=16, 256 threads, 4x4 micro-tile. M,Nc,K all % 64/16 == 0.
// ---------------------------------------------------------------------------
__global__ __launch_bounds__(256) void gemm_nt(
    const float* __restrict__ A, const float* __restrict__ B,
    const float* __restrict__ bias, float* __restrict__ Cm,
    int M, int Nc, int K)
{
    __shared__ float As[64][17];
    __shared__ float Bs[64][17];
    const int t  = threadIdx.x;
    const int tx = t & 15, ty = t >> 4;
    const int rowStart = blockIdx.y * 64, colStart = blockIdx.x * 64;
    const int lr = t >> 2;          // 0..63
    const int lk = (t & 3) * 4;     // 0,4,8,12
    float acc[4][4] = {};

    for (int k0 = 0; k0 < K; k0 += 16) {
        float4 av = *(const float4*)&A[(size_t)(rowStart + lr) * K + k0 + lk];
        float4 bv = *(const float4*)&B[(size_t)(colStart + lr) * K + k0 + lk];
        As[lr][lk] = av.x; As[lr][lk+1] = av.y; As[lr][lk+2] = av.z; As[lr][lk+3] = av.w;
        Bs[lr][lk] = bv.x; Bs[lr][lk+1] = bv.y; Bs[lr][lk+2] = bv.z; Bs[lr][lk+3] = bv.w;
        __syncthreads();
#pragma unroll
        for (int kk = 0; kk < 16; kk++) {
            float a[4], b[4];
#pragma unroll
            for (int i = 0; i < 4; i++) a[i] = As[ty*4 + i][kk];
#pragma unroll
            for (int j = 0; j < 4; j++) b[j] = Bs[tx*4 + j][kk];
#pragma unroll
            for (int i = 0; i < 4; i++)
#pragma unroll
                for (int j = 0; j < 4; j++) acc[i][j] += a[i] * b[j];
        }
        __syncthreads();
    }

    float b0 = bias[colStart + tx*4 + 0];
    float b1 = bias[colStart + tx*4 + 1];
    float b2 = bias[colStart + tx*4 + 2];
    float b3 = bias[colStart + tx*4 + 3];
#pragma unroll
    for (int i = 0; i < 4; i++) {
        float4 o;
        o.x = acc[i][0] + b0; o.y = acc[i][1] + b1;
        o.z = acc[i][2] + b2; o.w = acc[i][3] + b3;
        *(float4*)&Cm[(size_t)(rowStart + ty*4 + i) * Nc + colStart + tx*4] = o;
    }
}

// ---------------------------------------------------------------------------
// syrk + per-block top-4: si-tile = x[rows] @ x[cols]^T, 64x128 per block.
// Grid: (NSPLIT, N/64). Emits top-4 (val, col) per row per split.
// ---------------------------------------------------------------------------
__global__ __launch_bounds__(256) void syrk_topk(
    const float* __restrict__ x,
    float* __restrict__ cand_val, int* __restrict__ cand_idx)
{
    __shared__ float As[64][17];
    __shared__ float Bs[128][17];
    __shared__ float stile[64][128];
    __shared__ float pv[64][4][4];
    __shared__ int   pi[64][4][4];

    const int t  = threadIdx.x;
    const int tx = t & 15, ty = t >> 4;
    const int rowStart = blockIdx.y * 64;
    const int colStart = blockIdx.x * 128;
    const int lr = t >> 2;          // 0..63
    const int lk = (t & 3) * 4;     // 0,4,8,12
    float acc[4][8] = {};

    for (int k0 = 0; k0 < C_; k0 += 16) {
        float4 av = *(const float4*)&x[(size_t)(rowStart + lr) * C_ + k0 + lk];
        float4 c0 = *(const float4*)&x[(size_t)(colStart + lr) * C_ + k0 + lk];
        float4 c1 = *(const float4*)&x[(size_t)(colStart + 64 + lr) * C_ + k0 + lk];
        As[lr][lk] = av.x; As[lr][lk+1] = av.y; As[lr][lk+2] = av.z; As[lr][lk+3] = av.w;
        Bs[lr][lk] = c0.x; Bs[lr][lk+1] = c0.y; Bs[lr][lk+2] = c0.z; Bs[lr][lk+3] = c0.w;
        Bs[lr+64][lk] = c1.x; Bs[lr+64][lk+1] = c1.y; Bs[lr+64][lk+2] = c1.z; Bs[lr+64][lk+3] = c1.w;
        __syncthreads();
#pragma unroll
        for (int kk = 0; kk < 16; kk++) {
            float a[4], b[8];
#pragma unroll
            for (int i = 0; i < 4; i++) a[i] = As[ty*4 + i][kk];
#pragma unroll
            for (int j = 0; j < 8; j++) b[j] = Bs[tx + 16*j][kk];
#pragma unroll
            for (int i = 0; i < 4; i++)
#pragma unroll
                for (int j = 0; j < 8; j++) acc[i][j] += a[i] * b[j];
        }
        __syncthreads();
    }

    // spill si tile to LDS (local col = tx + 16*j)
#pragma unroll
    for (int i = 0; i < 4; i++)
#pragma unroll
        for (int j = 0; j < 8; j++) stile[ty*4 + i][tx + 16*j] = acc[i][j];
    __syncthreads();

    // per-slice top-4: 4 threads per row, 32 cols each
    {
        const int row = t >> 2, sl = t & 3;
        float bv[4] = {-1e30f, -1e30f, -1e30f, -1e30f};
        int   bi[4] = {-1, -1, -1, -1};
        for (int c = 0; c < 32; c++) {
            float vv = stile[row][sl*32 + c];
            if (vv > bv[3]) {
                int p = 3;
                while (p > 0 && bv[p-1] < vv) { bv[p] = bv[p-1]; bi[p] = bi[p-1]; p--; }
                bv[p] = vv; bi[p] = colStart + sl*32 + c;
            }
        }
#pragma unroll
        for (int m = 0; m < 4; m++) { pv[row][sl][m] = bv[m]; pi[row][sl][m] = bi[m]; }
    }
    __syncthreads();

    // merge 4 slices -> block top-4 per row, write to global candidate list
    if (t < 64) {
        float bv[4] = {-1e30f, -1e30f, -1e30f, -1e30f};
        int   bi[4] = {-1, -1, -1, -1};
        for (int sl = 0; sl < 4; sl++)
            for (int m = 0; m < 4; m++) {
                float vv = pv[t][sl][m];
                if (vv > bv[3]) {
                    int p = 3;
                    while (p > 0 && bv[p-1] < vv) { bv[p] = bv[p-1]; bi[p] = bi[p-1]; p--; }
                    bv[p] = vv; bi[p] = pi[t][sl][m];
                }
            }
        const size_t base = (size_t)(rowStart + t) * NCAND + blockIdx.x * 4;
#pragma unroll
        for (int m = 0; m < 4; m++) {
            cand_val[base + m] = bv[m];
            cand_idx[base + m] = bi[m];
        }
    }
}

// ---------------------------------------------------------------------------
// Per-row: fp32 top-NCHK of candidates -> exact fp64 re-check -> top-4
// threshold -> neighbor list + degree + dinv.  One block (256 thr) per row.
// ---------------------------------------------------------------------------
__global__ __launch_bounds__(256) void topk_merge(
    const float* __restrict__ x,
    const float* __restrict__ cand_val, const int* __restrict__ cand_idx,
    int* __restrict__ nbr_idx, int* __restrict__ nbr_cnt,
    float* __restrict__ dinv_arr)
{
    const int row = blockIdx.x;
    const int t = threadIdx.x;
    __shared__ float  sv[NCAND];
    __shared__ int    si[NCAND];
    __shared__ int    topi[NCHK];
    __shared__ double dv[NCHK];

    if (t < NCAND) {
        sv[t] = cand_val[(size_t)row * NCAND + t];
        si[t] = cand_idx[(size_t)row * NCAND + t];
    }
    __syncthreads();

    if (t == 0) {
        float bv[NCHK]; int bi[NCHK];
#pragma unroll
        for (int m = 0; m < NCHK; m++) { bv[m] = -1e30f; bi[m] = -1; }
        for (int c = 0; c < NCAND; c++) {
            float vv = sv[c];
            if (vv > bv[NCHK-1]) {
                int p = NCHK - 1;
                while (p > 0 && bv[p-1] < vv) { bv[p] = bv[p-1]; bi[p] = bi[p-1]; p--; }
                bv[p] = vv; bi[p] = si[c];
            }
        }
#pragma unroll
        for (int m = 0; m < NCHK; m++) topi[m] = bi[m];
    }
    __syncthreads();

    // exact fp64 dot products for the NCHK candidates
    const int wave = t >> 6, lane = t & 63;
    for (int c = wave; c < NCHK; c += 4) {
        const int j = topi[c];
        const float* xr = x + (size_t)row * C_;
        const float* xj = x + (size_t)j   * C_;
        double s = 0.0;
        for (int k = lane; k < C_; k += 64)
            s += (double)xr[k] * (double)xj[k];
#pragma unroll
        for (int o = 32; o > 0; o >>= 1) s += __shfl_down(s, o);
        if (lane == 0) dv[c] = s;
    }
    __syncthreads();

    if (t == 0) {
        double b4[4] = {-1e300, -1e300, -1e300, -1e300};
        for (int c = 0; c < NCHK; c++) {
            double vv = dv[c];
            if (vv > b4[3]) {
                int p = 3;
                while (p > 0 && b4[p-1] < vv) { b4[p] = b4[p-1]; p--; }
                b4[p] = vv;
            }
        }
        const double thr = b4[3];
        int cnt = 0;
        for (int c = 0; c < NCHK; c++)
            if (dv[c] >= thr && cnt < MAXN) { nbr_idx[(size_t)row * MAXN + cnt] = topi[c]; cnt++; }
        nbr_cnt[row]  = cnt;
        dinv_arr[row] = (float)(1.0 / sqrt((double)cnt));
    }
}

// ---------------------------------------------------------------------------
// z = u + dinv_i * sum_j dinv_j * v_j ; per-row BN (mean/var over C) ;
// h = relu(x + (z-mean)*rsqrt(var+eps)).  One block (256 thr) per row.
// ---------------------------------------------------------------------------
__global__ __launch_bounds__(256) void aggregate_bn(
    const float* __restrict__ x, const float* __restrict__ u,
    const float* __restrict__ v,
    const int* __restrict__ nbr_idx, const int* __restrict__ nbr_cnt,
    const float* __restrict__ dinv_arr, float* __restrict__ h)
{
    const int row = blockIdx.x;
    const int t = threadIdx.x;
    __shared__ int   s_nbr[MAXN];
    __shared__ float s_w[MAXN];
    __shared__ int   s_cnt;
    __shared__ float s_di;
    __shared__ float r1[4], r2[4];
    __shared__ float s_mean, s_istd;

    if (t == 0) { s_cnt = nbr_cnt[row]; s_di = dinv_arr[row]; }
    __syncthreads();
    const int cnt = s_cnt;
    if (t < cnt) {
        int j = nbr_idx[(size_t)row * MAXN + t];
        s_nbr[t] = j;
        s_w[t]   = dinv_arr[j];
    }
    __syncthreads();

    const float di = s_di;
    float z[2];
    float sum = 0.f, sumsq = 0.f;
#pragma unroll
    for (int e = 0; e < 2; e++) {
        const int c = t + e * 256;
        float s = 0.f;
        for (int m = 0; m < cnt; m++)
            s += s_w[m] * v[(size_t)s_nbr[m] * C_ + c];
        float zz = u[(size_t)row * C_ + c] + di * s;
        z[e] = zz;
        sum += zz; sumsq += zz * zz;
    }

    float a = sum, b = sumsq;
#pragma unroll
    for (int o = 32; o > 0; o >>= 1) { a += __shfl_down(a, o); b += __shfl_down(b, o); }
    const int wave = t >> 6, lane = t & 63;
    if (lane == 0) { r1[wave] = a; r2[wave] = b; }
    __syncthreads();
    if (t == 0) {
        float ta = r1[0] + r1[1] + r1[2] + r1[3];
        float tb = r2[0] + r2[1] + r2[2] + r2[3];
        float mean = ta / (float)C_;
        float var  = tb / (float)C_ - mean * mean;
        s_mean = mean;
        s_istd = 1.0f / sqrtf(var + EPSF);
    }
    __syncthreads();

    const float mean = s_mean, istd = s_istd;
#pragma unroll
    for (int e = 0; e < 2; e++) {
        const int c = t + e * 256;
        float hh = x[(size_t)row * C_ + c] + (z[e] - mean) * istd;
        h[(size_t)row * C_ + c] = fmaxf(hh, 0.f);
    }
}

// ---------------------------------------------------------------------------
extern "C" void kernel_launch(void* const* d_in, const int* in_sizes, int n_in,
                              void* d_out, int out_size, void* d_ws, size_t ws_size,
                              hipStream_t stream)
{
    const float* x    = (const float*)d_in[0];   // [N, C]
    const float* U_w  = (const float*)d_in[1];   // [C, C]
    const float* U_b  = (const float*)d_in[2];   // [C]
    const float* V_w  = (const float*)d_in[3];   // [C, C]
    const float* V_b  = (const float*)d_in[4];   // [C]
    const float* fc_w = (const float*)d_in[5];   // [OUT, C]
    const float* fc_b = (const float*)d_in[6];   // [OUT]
    float* out = (float*)d_out;                  // [N, OUT]

    // workspace carve-up (~30 MB)
    float* v_buf    = (float*)d_ws;                       // N*C
    float* u_buf    = v_buf + (size_t)N_ * C_;            // N*C
    float* h_buf    = u_buf + (size_t)N_ * C_;            // N*C
    float* cand_val = h_buf + (size_t)N_ * C_;            // N*NCAND
    int*   cand_idx = (int*)(cand_val + (size_t)N_ * NCAND); // N*NCAND
    int*   nbr_idx  = cand_idx + (size_t)N_ * NCAND;      // N*MAXN
    int*   nbr_cnt  = nbr_idx + (size_t)N_ * MAXN;        // N
    float* dinv     = (float*)(nbr_cnt + N_);             // N

    // v = x @ V_w.T + V_b ; u = x @ U_w.T + U_b
    dim3 gProj(C_ / 64, N_ / 64);
    hipLaunchKernelGGL(gemm_nt, gProj, dim3(256), 0, stream, x, V_w, V_b, v_buf, N_, C_, C_);
    hipLaunchKernelGGL(gemm_nt, gProj, dim3(256), 0, stream, x, U_w, U_b, u_buf, N_, C_, C_);

    // similarity + per-split top-4 candidates
    hipLaunchKernelGGL(syrk_topk, dim3(NSPLIT, N_ / 64), dim3(256), 0, stream,
                       x, cand_val, cand_idx);

    // exact merge -> neighbors, deg, dinv
    hipLaunchKernelGGL(topk_merge, dim3(N_), dim3(256), 0, stream,
                       x, cand_val, cand_idx, nbr_idx, nbr_cnt, dinv);

    // aggregate + BN + relu -> h
    hipLaunchKernelGGL(aggregate_bn, dim3(N_), dim3(256), 0, stream,
                       x, u_buf, v_buf, nbr_idx, nbr_cnt, dinv, h_buf);

    // out = h @ fc_w.T + fc_b
    dim3 gFc(OUT_ / 64, N_ / 64);
    hipLaunchKernelGGL(gemm_nt, gFc, dim3(256), 0, stream, h_buf, fc_w, fc_b, out, N_, OUT_, C_);
}

// Round 2
// 525.211 us; speedup vs baseline: 1.2599x; 1.2599x over previous
//
#include <hip/hip_runtime.h>
#include <cstddef>

#define N_    4096
#define C_    512
#define OUT_  256
#define EPSF  1e-5f

#define NSPLIT 32          // 128-col splits
#define NSEL   6           // top-6 kept per split (safety for bf16 similarity)
#define NCAND  (NSPLIT*NSEL)  // 192 candidates per row
#define NCHK   16          // candidates re-checked in fp64
#define MAXN   16          // max stored neighbors

typedef __attribute__((ext_vector_type(8))) short short8;
typedef __attribute__((ext_vector_type(4))) float f32x4;

__device__ __forceinline__ unsigned short f2bf(float f) {
    union { float f; unsigned u; } v; v.f = f;
    unsigned r = (v.u + 0x7FFFu + ((v.u >> 16) & 1u)) >> 16;
    return (unsigned short)r;
}
__device__ __forceinline__ float bf2f(unsigned short h) {
    union { unsigned u; float f; } v; v.u = ((unsigned)h) << 16;
    return v.f;
}

// ---------------------------------------------------------------------------
// Split each fp32 into hi/lo bf16 planes: x ~= hi + lo (lo = bf16(x - hi)).
// n4 = element_count / 4.
// ---------------------------------------------------------------------------
__global__ __launch_bounds__(256) void split_bf16_kernel(
    const float* __restrict__ src, unsigned short* __restrict__ hi,
    unsigned short* __restrict__ lo, int n4)
{
    int i = blockIdx.x * 256 + threadIdx.x;
    if (i >= n4) return;
    float4 f = ((const float4*)src)[i];
    ushort4 h, l;
    h.x = f2bf(f.x); l.x = f2bf(f.x - bf2f(h.x));
    h.y = f2bf(f.y); l.y = f2bf(f.y - bf2f(h.y));
    h.z = f2bf(f.z); l.z = f2bf(f.z - bf2f(h.z));
    h.w = f2bf(f.w); l.w = f2bf(f.w - bf2f(h.w));
    ((ushort4*)hi)[i] = h;
    ((ushort4*)lo)[i] = l;
}

// ---------------------------------------------------------------------------
// MFMA syrk + fused per-split top-6.
// 128x128 tile / block (4 waves, each 64x64 = 4x4 MFMA tiles of 16x16x32).
// After the K loop the staging LDS is reused (union) for a bf16 score tile;
// 2 threads/row scan it maintaining running top-6, then pairwise merge.
// ---------------------------------------------------------------------------
#define SA 72   // staging LDS stride (bf16 elems): 64 + 8 -> conflict-free-ish
#define ST 67   // stile stride (ushort)

union SyrkSmem {
    struct { unsigned short A[128 * SA]; unsigned short B[128 * SA]; } stg;  // 36,864 B
    struct { unsigned short stile[128 * ST]; float pv[256 * NSEL]; int pi[256 * NSEL]; } sel;
};

__global__ __launch_bounds__(256) void syrk_topk_mfma(
    const unsigned short* __restrict__ xb,
    float* __restrict__ cand_val, int* __restrict__ cand_idx)
{
    __shared__ SyrkSmem sm;
    const int t = threadIdx.x;
    const int lane = t & 63, w = t >> 6;
    const int wr = w >> 1, wc = w & 1;
    const int col16 = lane & 15, quad = lane >> 4;
    const int rowStart = blockIdx.y * 128, colStart = blockIdx.x * 128;

    f32x4 acc[4][4] = {};

    for (int k0 = 0; k0 < C_; k0 += 64) {
        int4 ra[4], rb[4];
#pragma unroll
        for (int i = 0; i < 4; i++) {
            int idx = i * 256 + t;            // 0..1023 : 128 rows x 8 chunks
            int row = idx >> 3, ch = idx & 7;
            ra[i] = *(const int4*)&xb[(size_t)(rowStart + row) * C_ + k0 + ch * 8];
            rb[i] = *(const int4*)&xb[(size_t)(colStart + row) * C_ + k0 + ch * 8];
        }
        __syncthreads();
#pragma unroll
        for (int i = 0; i < 4; i++) {
            int idx = i * 256 + t;
            int row = idx >> 3, ch = idx & 7;
            *(int4*)&sm.stg.A[row * SA + ch * 8] = ra[i];
            *(int4*)&sm.stg.B[row * SA + ch * 8] = rb[i];
        }
        __syncthreads();
#pragma unroll
        for (int ks = 0; ks < 2; ks++) {
            short8 af[4], bfr[4];
#pragma unroll
            for (int mt = 0; mt < 4; mt++)
                af[mt] = *(const short8*)&sm.stg.A[(wr*64 + mt*16 + col16) * SA + ks*32 + quad*8];
#pragma unroll
            for (int nt = 0; nt < 4; nt++)
                bfr[nt] = *(const short8*)&sm.stg.B[(wc*64 + nt*16 + col16) * SA + ks*32 + quad*8];
#pragma unroll
            for (int mt = 0; mt < 4; mt++)
#pragma unroll
                for (int nt = 0; nt < 4; nt++)
                    acc[mt][nt] = __builtin_amdgcn_mfma_f32_16x16x32_bf16(
                        af[mt], bfr[nt], acc[mt][nt], 0, 0, 0);
        }
        __syncthreads();
    }

    // ---- fused selection: two half-passes (cols 0-63 then 64-127) ----
    float bv[NSEL]; int bi[NSEL];
#pragma unroll
    for (int m = 0; m < NSEL; m++) { bv[m] = -1e30f; bi[m] = -1; }
    const int srow = t >> 1, ss = t & 1;

    for (int p = 0; p < 2; p++) {
        if (wc == p) {
#pragma unroll
            for (int mt = 0; mt < 4; mt++)
#pragma unroll
                for (int nt = 0; nt < 4; nt++)
#pragma unroll
                    for (int r = 0; r < 4; r++)
                        sm.sel.stile[(wr*64 + mt*16 + quad*4 + r) * ST + nt*16 + col16] =
                            f2bf(acc[mt][nt][r]);
        }
        __syncthreads();
        for (int c = 0; c < 32; c++) {
            float vv = bf2f(sm.sel.stile[srow * ST + ss*32 + c]);
            if (vv > bv[NSEL-1]) {
                int gc = colStart + p*64 + ss*32 + c;
                int q = NSEL - 1;
                while (q > 0 && bv[q-1] < vv) { bv[q] = bv[q-1]; bi[q] = bi[q-1]; q--; }
                bv[q] = vv; bi[q] = gc;
            }
        }
        __syncthreads();
    }
#pragma unroll
    for (int m = 0; m < NSEL; m++) { sm.sel.pv[t*NSEL + m] = bv[m]; sm.sel.pi[t*NSEL + m] = bi[m]; }
    __syncthreads();

    if (t < 128) {
        float mv[NSEL]; int mi[NSEL];
#pragma unroll
        for (int m = 0; m < NSEL; m++) { mv[m] = -1e30f; mi[m] = -1; }
        for (int sId = 0; sId < 2; sId++)
            for (int m2 = 0; m2 < NSEL; m2++) {
                float vv = sm.sel.pv[(t*2 + sId)*NSEL + m2];
                if (vv > mv[NSEL-1]) {
                    int ii = sm.sel.pi[(t*2 + sId)*NSEL + m2];
                    int q = NSEL - 1;
                    while (q > 0 && mv[q-1] < vv) { mv[q] = mv[q-1]; mi[q] = mi[q-1]; q--; }
                    mv[q] = vv; mi[q] = ii;
                }
            }
        const size_t base = (size_t)(rowStart + t) * NCAND + blockIdx.x * NSEL;
#pragma unroll
        for (int m = 0; m < NSEL; m++) {
            cand_val[base + m] = mv[m];
            cand_idx[base + m] = mi[m];
        }
    }
}

// ---------------------------------------------------------------------------
// Split-bf16 GEMM: out[M,Nc] = (Ah+Al)[M,512] @ (Bh+Bl)[Nc,512]^T + bias.
// Tile 128x64, 4 waves (each 64x32 = 4x2 tiles), BK=32, 3 MFMAs per tile.
// ---------------------------------------------------------------------------
#define GS 40   // staging stride (bf16 elems): 32 + 8

__global__ __launch_bounds__(256) void gemm_split(
    const unsigned short* __restrict__ Ah, const unsigned short* __restrict__ Al,
    const unsigned short* __restrict__ Bh, const unsigned short* __restrict__ Bl,
    const float* __restrict__ bias, float* __restrict__ out, int Nc)
{
    __shared__ unsigned short sAh[128 * GS], sAl[128 * GS];
    __shared__ unsigned short sBh[64 * GS],  sBl[64 * GS];
    const int t = threadIdx.x;
    const int lane = t & 63, w = t >> 6;
    const int wr = w >> 1, wc = w & 1;
    const int col16 = lane & 15, quad = lane >> 4;
    const int rowStart = blockIdx.y * 128, colStart = blockIdx.x * 64;

    f32x4 acc[4][2] = {};

    for (int k0 = 0; k0 < C_; k0 += 32) {
        int4 rg[6];
#pragma unroll
        for (int i = 0; i < 6; i++) {
            int idx = i * 256 + t;  // [0,512)=Ah [512,1024)=Al [1024,1280)=Bh [1280,1536)=Bl
            const unsigned short* src;
            int row, ch;
            if (idx < 1024) {
                int pl = idx >> 9, rem = idx & 511; row = rem >> 2; ch = rem & 3;
                src = (pl ? Al : Ah) + (size_t)(rowStart + row) * C_;
            } else {
                int rem = idx - 1024; int pl = rem >> 8; rem &= 255; row = rem >> 2; ch = rem & 3;
                src = (pl ? Bl : Bh) + (size_t)(colStart + row) * C_;
            }
            rg[i] = *(const int4*)&src[k0 + ch * 8];
        }
        __syncthreads();
#pragma unroll
        for (int i = 0; i < 6; i++) {
            int idx = i * 256 + t;
            unsigned short* dst;
            int row, ch;
            if (idx < 1024) {
                int pl = idx >> 9, rem = idx & 511; row = rem >> 2; ch = rem & 3;
                dst = (pl ? sAl : sAh) + row * GS;
            } else {
                int rem = idx - 1024; int pl = rem >> 8; rem &= 255; row = rem >> 2; ch = rem & 3;
                dst = (pl ? sBl : sBh) + row * GS;
            }
            *(int4*)&dst[ch * 8] = rg[i];
        }
        __syncthreads();

        short8 ah[4], al[4], bh[2], bl[2];
#pragma unroll
        for (int mt = 0; mt < 4; mt++) {
            int ro = (wr*64 + mt*16 + col16) * GS + quad*8;
            ah[mt] = *(const short8*)&sAh[ro];
            al[mt] = *(const short8*)&sAl[ro];
        }
#pragma unroll
        for (int nt = 0; nt < 2; nt++) {
            int ro = (wc*32 + nt*16 + col16) * GS + quad*8;
            bh[nt] = *(const short8*)&sBh[ro];
            bl[nt] = *(const short8*)&sBl[ro];
        }
#pragma unroll
        for (int mt = 0; mt < 4; mt++)
#pragma unroll
            for (int nt = 0; nt < 2; nt++) {
                acc[mt][nt] = __builtin_amdgcn_mfma_f32_16x16x32_bf16(al[mt], bh[nt], acc[mt][nt], 0, 0, 0);
                acc[mt][nt] = __builtin_amdgcn_mfma_f32_16x16x32_bf16(ah[mt], bl[nt], acc[mt][nt], 0, 0, 0);
                acc[mt][nt] = __builtin_amdgcn_mfma_f32_16x16x32_bf16(ah[mt], bh[nt], acc[mt][nt], 0, 0, 0);
            }
        __syncthreads();
    }

#pragma unroll
    for (int nt = 0; nt < 2; nt++) {
        const int col = colStart + wc*32 + nt*16 + col16;
        const float bns = bias[col];
#pragma unroll
        for (int mt = 0; mt < 4; mt++)
#pragma unroll
            for (int r = 0; r < 4; r++) {
                const int row = rowStart + wr*64 + mt*16 + quad*4 + r;
                out[(size_t)row * Nc + col] = acc[mt][nt][r] + bns;
            }
    }
}

// ---------------------------------------------------------------------------
// Per-row: fp32 top-NCHK of candidates -> exact fp64 re-check -> top-4
// threshold -> neighbor list + degree + dinv.  One block (256 thr) per row.
// ---------------------------------------------------------------------------
__global__ __launch_bounds__(256) void topk_merge(
    const float* __restrict__ x,
    const float* __restrict__ cand_val, const int* __restrict__ cand_idx,
    int* __restrict__ nbr_idx, int* __restrict__ nbr_cnt,
    float* __restrict__ dinv_arr)
{
    const int row = blockIdx.x;
    const int t = threadIdx.x;
    __shared__ float  sv[NCAND];
    __shared__ int    si[NCAND];
    __shared__ int    topi[NCHK];
    __shared__ double dv[NCHK];

    if (t < NCAND) {
        sv[t] = cand_val[(size_t)row * NCAND + t];
        si[t] = cand_idx[(size_t)row * NCAND + t];
    }
    __syncthreads();

    if (t == 0) {
        float bv[NCHK]; int bi[NCHK];
#pragma unroll
        for (int m = 0; m < NCHK; m++) { bv[m] = -1e30f; bi[m] = -1; }
        for (int c = 0; c < NCAND; c++) {
            float vv = sv[c];
            if (vv > bv[NCHK-1]) {
                int p = NCHK - 1;
                while (p > 0 && bv[p-1] < vv) { bv[p] = bv[p-1]; bi[p] = bi[p-1]; p--; }
                bv[p] = vv; bi[p] = si[c];
            }
        }
#pragma unroll
        for (int m = 0; m < NCHK; m++) topi[m] = bi[m];
    }
    __syncthreads();

    const int wave = t >> 6, lane = t & 63;
    for (int c = wave; c < NCHK; c += 4) {
        const int j = topi[c];
        const float* xr = x + (size_t)row * C_;
        const float* xj = x + (size_t)j   * C_;
        double s = 0.0;
        for (int k = lane; k < C_; k += 64)
            s += (double)xr[k] * (double)xj[k];
#pragma unroll
        for (int o = 32; o > 0; o >>= 1) s += __shfl_down(s, o);
        if (lane == 0) dv[c] = s;
    }
    __syncthreads();

    if (t == 0) {
        double b4[4] = {-1e300, -1e300, -1e300, -1e300};
        for (int c = 0; c < NCHK; c++) {
            double vv = dv[c];
            if (vv > b4[3]) {
                int p = 3;
                while (p > 0 && b4[p-1] < vv) { b4[p] = b4[p-1]; p--; }
                b4[p] = vv;
            }
        }
        const double thr = b4[3];
        int cnt = 0;
        for (int c = 0; c < NCHK; c++)
            if (dv[c] >= thr && cnt < MAXN) { nbr_idx[(size_t)row * MAXN + cnt] = topi[c]; cnt++; }
        nbr_cnt[row]  = cnt;
        dinv_arr[row] = (float)(1.0 / sqrt((double)cnt));
    }
}

// ---------------------------------------------------------------------------
// z = u + dinv_i * sum_j dinv_j * v_j ; per-row BN over C ; relu(x + norm) ;
// emit h pre-split into bf16 hi/lo planes for the fc MFMA GEMM.
// ---------------------------------------------------------------------------
__global__ __launch_bounds__(256) void aggregate_bn(
    const float* __restrict__ x, const float* __restrict__ u,
    const float* __restrict__ v,
    const int* __restrict__ nbr_idx, const int* __restrict__ nbr_cnt,
    const float* __restrict__ dinv_arr,
    unsigned short* __restrict__ hh, unsigned short* __restrict__ hl)
{
    const int row = blockIdx.x;
    const int t = threadIdx.x;
    __shared__ int   s_nbr[MAXN];
    __shared__ float s_w[MAXN];
    __shared__ int   s_cnt;
    __shared__ float s_di;
    __shared__ float r1[4], r2[4];
    __shared__ float s_mean, s_istd;

    if (t == 0) { s_cnt = nbr_cnt[row]; s_di = dinv_arr[row]; }
    __syncthreads();
    const int cnt = s_cnt;
    if (t < cnt) {
        int j = nbr_idx[(size_t)row * MAXN + t];
        s_nbr[t] = j;
        s_w[t]   = dinv_arr[j];
    }
    __syncthreads();

    const float di = s_di;
    float z[2];
    float sum = 0.f, sumsq = 0.f;
#pragma unroll
    for (int e = 0; e < 2; e++) {
        const int c = t + e * 256;
        float s = 0.f;
        for (int m = 0; m < cnt; m++)
            s += s_w[m] * v[(size_t)s_nbr[m] * C_ + c];
        float zz = u[(size_t)row * C_ + c] + di * s;
        z[e] = zz;
        sum += zz; sumsq += zz * zz;
    }

    float a = sum, b = sumsq;
#pragma unroll
    for (int o = 32; o > 0; o >>= 1) { a += __shfl_down(a, o); b += __shfl_down(b, o); }
    const int wave = t >> 6, lane = t & 63;
    if (lane == 0) { r1[wave] = a; r2[wave] = b; }
    __syncthreads();
    if (t == 0) {
        float ta = r1[0] + r1[1] + r1[2] + r1[3];
        float tb = r2[0] + r2[1] + r2[2] + r2[3];
        float mean = ta / (float)C_;
        float var  = tb / (float)C_ - mean * mean;
        s_mean = mean;
        s_istd = 1.0f / sqrtf(var + EPSF);
    }
    __syncthreads();

    const float mean = s_mean, istd = s_istd;
#pragma unroll
    for (int e = 0; e < 2; e++) {
        const int c = t + e * 256;
        float hhv = fmaxf(x[(size_t)row * C_ + c] + (z[e] - mean) * istd, 0.f);
        unsigned short hb = f2bf(hhv);
        hh[(size_t)row * C_ + c] = hb;
        hl[(size_t)row * C_ + c] = f2bf(hhv - bf2f(hb));
    }
}

// ---------------------------------------------------------------------------
extern "C" void kernel_launch(void* const* d_in, const int* in_sizes, int n_in,
                              void* d_out, int out_size, void* d_ws, size_t ws_size,
                              hipStream_t stream)
{
    const float* x    = (const float*)d_in[0];   // [N, C]
    const float* U_w  = (const float*)d_in[1];   // [C, C]
    const float* U_b  = (const float*)d_in[2];   // [C]
    const float* V_w  = (const float*)d_in[3];   // [C, C]
    const float* V_b  = (const float*)d_in[4];   // [C]
    const float* fc_w = (const float*)d_in[5];   // [OUT, C]
    const float* fc_b = (const float*)d_in[6];   // [OUT]
    float* out = (float*)d_out;                  // [N, OUT]

    // ---- workspace carve-up (~43 MB) ----
    char* p = (char*)d_ws;
    auto alloc = [&](size_t bytes) { char* r = p; p += (bytes + 255) & ~(size_t)255; return r; };
    unsigned short* xh = (unsigned short*)alloc((size_t)N_ * C_ * 2);
    unsigned short* xl = (unsigned short*)alloc((size_t)N_ * C_ * 2);
    unsigned short* uh = (unsigned short*)alloc((size_t)C_ * C_ * 2);
    unsigned short* ul = (unsigned short*)alloc((size_t)C_ * C_ * 2);
    unsigned short* vh = (unsigned short*)alloc((size_t)C_ * C_ * 2);
    unsigned short* vl = (unsigned short*)alloc((size_t)C_ * C_ * 2);
    unsigned short* fh = (unsigned short*)alloc((size_t)OUT_ * C_ * 2);
    unsigned short* fl = (unsigned short*)alloc((size_t)OUT_ * C_ * 2);
    unsigned short* hh = (unsigned short*)alloc((size_t)N_ * C_ * 2);
    unsigned short* hl = (unsigned short*)alloc((size_t)N_ * C_ * 2);
    float* u_buf    = (float*)alloc((size_t)N_ * C_ * 4);
    float* v_buf    = (float*)alloc((size_t)N_ * C_ * 4);
    float* cand_val = (float*)alloc((size_t)N_ * NCAND * 4);
    int*   cand_idx = (int*)  alloc((size_t)N_ * NCAND * 4);
    int*   nbr_idx  = (int*)  alloc((size_t)N_ * MAXN * 4);
    int*   nbr_cnt  = (int*)  alloc((size_t)N_ * 4);
    float* dinv     = (float*)alloc((size_t)N_ * 4);

    // ---- split fp32 -> bf16 hi/lo planes ----
    hipLaunchKernelGGL(split_bf16_kernel, dim3(N_*C_/4/256), dim3(256), 0, stream, x, xh, xl, N_*C_/4);
    hipLaunchKernelGGL(split_bf16_kernel, dim3(C_*C_/4/256), dim3(256), 0, stream, U_w, uh, ul, C_*C_/4);
    hipLaunchKernelGGL(split_bf16_kernel, dim3(C_*C_/4/256), dim3(256), 0, stream, V_w, vh, vl, C_*C_/4);
    hipLaunchKernelGGL(split_bf16_kernel, dim3(OUT_*C_/4/256), dim3(256), 0, stream, fc_w, fh, fl, OUT_*C_/4);

    // ---- similarity (bf16 MFMA) + per-split top-6 candidates ----
    hipLaunchKernelGGL(syrk_topk_mfma, dim3(N_/128, N_/128), dim3(256), 0, stream,
                       xh, cand_val, cand_idx);

    // ---- exact merge -> neighbors, deg, dinv ----
    hipLaunchKernelGGL(topk_merge, dim3(N_), dim3(256), 0, stream,
                       x, cand_val, cand_idx, nbr_idx, nbr_cnt, dinv);

    // ---- u = x @ U_w.T + U_b ; v = x @ V_w.T + V_b (split-bf16 MFMA) ----
    hipLaunchKernelGGL(gemm_split, dim3(C_/64, N_/128), dim3(256), 0, stream,
                       xh, xl, uh, ul, U_b, u_buf, C_);
    hipLaunchKernelGGL(gemm_split, dim3(C_/64, N_/128), dim3(256), 0, stream,
                       xh, xl, vh, vl, V_b, v_buf, C_);

    // ---- aggregate + BN + relu -> h (bf16 split) ----
    hipLaunchKernelGGL(aggregate_bn, dim3(N_), dim3(256), 0, stream,
                       x, u_buf, v_buf, nbr_idx, nbr_cnt, dinv, hh, hl);

    // ---- out = h @ fc_w.T + fc_b ----
    hipLaunchKernelGGL(gemm_split, dim3(OUT_/64, N_/128), dim3(256), 0, stream,
                       hh, hl, fh, fl, fc_b, out, OUT_);
}

// Round 3
// 360.891 us; speedup vs baseline: 1.8336x; 1.4553x over previous
//
#include <hip/hip_runtime.h>
#include <cstddef>

#define N_    4096
#define C_    512
#define OUT_  256
#define EPSF  1e-5f

#define NSPLIT 32          // 128-col splits
#define NSEL   6           // top-6 kept per split (safety for bf16 similarity)
#define NCAND  (NSPLIT*NSEL)  // 192 candidates per row
#define NCHK   16          // candidates re-checked in fp64
#define MAXN   16          // max stored neighbors

typedef __attribute__((ext_vector_type(8))) short short8;
typedef __attribute__((ext_vector_type(4))) float f32x4;

__device__ __forceinline__ unsigned short f2bf(float f) {
    union { float f; unsigned u; } v; v.f = f;
    unsigned r = (v.u + 0x7FFFu + ((v.u >> 16) & 1u)) >> 16;
    return (unsigned short)r;
}
__device__ __forceinline__ float bf2f(unsigned short h) {
    union { unsigned u; float f; } v; v.u = ((unsigned)h) << 16;
    return v.f;
}

// Branchless constant-index top-6 insert (descending). All indices are
// compile-time -> stays in VGPRs (dynamic-index version went to scratch:
// R2 syrk showed 137 MB WRITE_SIZE for a 6 MB output).
struct Top6 { float v[NSEL]; int i[NSEL]; };
__device__ __forceinline__ void top6_init(Top6& s) {
#pragma unroll
    for (int m = 0; m < NSEL; m++) { s.v[m] = -1e30f; s.i[m] = -1; }
}
__device__ __forceinline__ void top6_insert(Top6& s, float vv, int gc) {
    if (vv <= s.v[5]) return;
    bool g0 = vv > s.v[0], g1 = vv > s.v[1], g2 = vv > s.v[2],
         g3 = vv > s.v[3], g4 = vv > s.v[4];
    s.v[5] = g4 ? s.v[4] : vv;                  s.i[5] = g4 ? s.i[4] : gc;
    s.v[4] = g3 ? s.v[3] : (g4 ? vv : s.v[4]);  s.i[4] = g3 ? s.i[3] : (g4 ? gc : s.i[4]);
    s.v[3] = g2 ? s.v[2] : (g3 ? vv : s.v[3]);  s.i[3] = g2 ? s.i[2] : (g3 ? gc : s.i[3]);
    s.v[2] = g1 ? s.v[1] : (g2 ? vv : s.v[2]);  s.i[2] = g1 ? s.i[1] : (g2 ? gc : s.i[2]);
    s.v[1] = g0 ? s.v[0] : (g1 ? vv : s.v[1]);  s.i[1] = g0 ? s.i[0] : (g1 ? gc : s.i[1]);
    s.v[0] = g0 ? vv : s.v[0];                  s.i[0] = g0 ? gc : s.i[0];
}

// ---------------------------------------------------------------------------
// Split each fp32 into hi/lo bf16 planes: x ~= hi + lo.
// ---------------------------------------------------------------------------
__global__ __launch_bounds__(256) void split_bf16_kernel(
    const float* __restrict__ src, unsigned short* __restrict__ hi,
    unsigned short* __restrict__ lo, int n4)
{
    int i = blockIdx.x * 256 + threadIdx.x;
    if (i >= n4) return;
    float4 f = ((const float4*)src)[i];
    ushort4 h, l;
    h.x = f2bf(f.x); l.x = f2bf(f.x - bf2f(h.x));
    h.y = f2bf(f.y); l.y = f2bf(f.y - bf2f(h.y));
    h.z = f2bf(f.z); l.z = f2bf(f.z - bf2f(h.z));
    h.w = f2bf(f.w); l.w = f2bf(f.w - bf2f(h.w));
    ((ushort4*)hi)[i] = h;
    ((ushort4*)lo)[i] = l;
}

// ---------------------------------------------------------------------------
// MFMA syrk + fused per-split top-6. 128x128 tile / block.
// Selection now uses fp32 stile (stride 65 -> 2-way conflicts = free) and
// branchless register-resident top-6.
// ---------------------------------------------------------------------------
#define SA  72   // staging stride (bf16 elems)
#define STF 65   // fp32 stile stride

union SyrkSmem {
    struct { unsigned short A[128 * SA]; unsigned short B[128 * SA]; } stg;  // 36,864 B
    struct { float stile[128 * STF]; float pv[256 * NSEL]; int pi[256 * NSEL]; } sel; // 45,568 B
};

__global__ __launch_bounds__(256) void syrk_topk_mfma(
    const unsigned short* __restrict__ xb,
    float* __restrict__ cand_val, int* __restrict__ cand_idx)
{
    __shared__ SyrkSmem sm;
    const int t = threadIdx.x;
    const int lane = t & 63, w = t >> 6;
    const int wr = w >> 1, wc = w & 1;
    const int col16 = lane & 15, quad = lane >> 4;
    const int rowStart = blockIdx.y * 128, colStart = blockIdx.x * 128;

    f32x4 acc[4][4] = {};

    for (int k0 = 0; k0 < C_; k0 += 64) {
        int4 ra[4], rb[4];
#pragma unroll
        for (int i = 0; i < 4; i++) {
            int idx = i * 256 + t;            // 128 rows x 8 chunks
            int row = idx >> 3, ch = idx & 7;
            ra[i] = *(const int4*)&xb[(size_t)(rowStart + row) * C_ + k0 + ch * 8];
            rb[i] = *(const int4*)&xb[(size_t)(colStart + row) * C_ + k0 + ch * 8];
        }
        __syncthreads();
#pragma unroll
        for (int i = 0; i < 4; i++) {
            int idx = i * 256 + t;
            int row = idx >> 3, ch = idx & 7;
            *(int4*)&sm.stg.A[row * SA + ch * 8] = ra[i];
            *(int4*)&sm.stg.B[row * SA + ch * 8] = rb[i];
        }
        __syncthreads();
#pragma unroll
        for (int ks = 0; ks < 2; ks++) {
            short8 af[4], bfr[4];
#pragma unroll
            for (int mt = 0; mt < 4; mt++)
                af[mt] = *(const short8*)&sm.stg.A[(wr*64 + mt*16 + col16) * SA + ks*32 + quad*8];
#pragma unroll
            for (int nt = 0; nt < 4; nt++)
                bfr[nt] = *(const short8*)&sm.stg.B[(wc*64 + nt*16 + col16) * SA + ks*32 + quad*8];
#pragma unroll
            for (int mt = 0; mt < 4; mt++)
#pragma unroll
                for (int nt = 0; nt < 4; nt++)
                    acc[mt][nt] = __builtin_amdgcn_mfma_f32_16x16x32_bf16(
                        af[mt], bfr[nt], acc[mt][nt], 0, 0, 0);
        }
        __syncthreads();
    }
    __syncthreads();   // drain last fragment reads before stile overwrites stg

    // ---- fused selection: two half-passes (cols 0-63 then 64-127) ----
    Top6 tk; top6_init(tk);
    const int srow = t >> 1, ss = t & 1;

    for (int p = 0; p < 2; p++) {
        if (wc == p) {
#pragma unroll
            for (int mt = 0; mt < 4; mt++)
#pragma unroll
                for (int nt = 0; nt < 4; nt++)
#pragma unroll
                    for (int r = 0; r < 4; r++)
                        sm.sel.stile[(wr*64 + mt*16 + quad*4 + r) * STF + nt*16 + col16] =
                            acc[mt][nt][r];
        }
        __syncthreads();
#pragma unroll
        for (int c = 0; c < 32; c++) {
            float vv = sm.sel.stile[srow * STF + ss*32 + c];
            top6_insert(tk, vv, colStart + p*64 + ss*32 + c);
        }
        __syncthreads();
    }
#pragma unroll
    for (int m = 0; m < NSEL; m++) { sm.sel.pv[t*NSEL + m] = tk.v[m]; sm.sel.pi[t*NSEL + m] = tk.i[m]; }
    __syncthreads();

    if (t < 128) {
        Top6 mk; top6_init(mk);
        for (int sId = 0; sId < 2; sId++)
#pragma unroll
            for (int m2 = 0; m2 < NSEL; m2++)
                top6_insert(mk, sm.sel.pv[(t*2 + sId)*NSEL + m2], sm.sel.pi[(t*2 + sId)*NSEL + m2]);
        const size_t base = (size_t)(rowStart + t) * NCAND + blockIdx.x * NSEL;
#pragma unroll
        for (int m = 0; m < NSEL; m++) {
            cand_val[base + m] = mk.v[m];
            cand_idx[base + m] = mk.i[m];
        }
    }
}

// ---------------------------------------------------------------------------
// Split-bf16 GEMM: out[M,Nc] = (Ah+Al)[M,512] @ (Bh+Bl)[Nc,512]^T + bias.
// ---------------------------------------------------------------------------
#define GS 40   // staging stride (bf16 elems)

__global__ __launch_bounds__(256) void gemm_split(
    const unsigned short* __restrict__ Ah, const unsigned short* __restrict__ Al,
    const unsigned short* __restrict__ Bh, const unsigned short* __restrict__ Bl,
    const float* __restrict__ bias, float* __restrict__ out, int Nc)
{
    __shared__ unsigned short sAh[128 * GS], sAl[128 * GS];
    __shared__ unsigned short sBh[64 * GS],  sBl[64 * GS];
    const int t = threadIdx.x;
    const int lane = t & 63, w = t >> 6;
    const int wr = w >> 1, wc = w & 1;
    const int col16 = lane & 15, quad = lane >> 4;
    const int rowStart = blockIdx.y * 128, colStart = blockIdx.x * 64;

    f32x4 acc[4][2] = {};

    for (int k0 = 0; k0 < C_; k0 += 32) {
        int4 rg[6];
#pragma unroll
        for (int i = 0; i < 6; i++) {
            int idx = i * 256 + t;
            const unsigned short* src;
            int row, ch;
            if (idx < 1024) {
                int pl = idx >> 9, rem = idx & 511; row = rem >> 2; ch = rem & 3;
                src = (pl ? Al : Ah) + (size_t)(rowStart + row) * C_;
            } else {
                int rem = idx - 1024; int pl = rem >> 8; rem &= 255; row = rem >> 2; ch = rem & 3;
                src = (pl ? Bl : Bh) + (size_t)(colStart + row) * C_;
            }
            rg[i] = *(const int4*)&src[k0 + ch * 8];
        }
        __syncthreads();
#pragma unroll
        for (int i = 0; i < 6; i++) {
            int idx = i * 256 + t;
            unsigned short* dst;
            int row, ch;
            if (idx < 1024) {
                int pl = idx >> 9, rem = idx & 511; row = rem >> 2; ch = rem & 3;
                dst = (pl ? sAl : sAh) + row * GS;
            } else {
                int rem = idx - 1024; int pl = rem >> 8; rem &= 255; row = rem >> 2; ch = rem & 3;
                dst = (pl ? sBl : sBh) + row * GS;
            }
            *(int4*)&dst[ch * 8] = rg[i];
        }
        __syncthreads();

        short8 ah[4], al[4], bh[2], bl[2];
#pragma unroll
        for (int mt = 0; mt < 4; mt++) {
            int ro = (wr*64 + mt*16 + col16) * GS + quad*8;
            ah[mt] = *(const short8*)&sAh[ro];
            al[mt] = *(const short8*)&sAl[ro];
        }
#pragma unroll
        for (int nt = 0; nt < 2; nt++) {
            int ro = (wc*32 + nt*16 + col16) * GS + quad*8;
            bh[nt] = *(const short8*)&sBh[ro];
            bl[nt] = *(const short8*)&sBl[ro];
        }
#pragma unroll
        for (int mt = 0; mt < 4; mt++)
#pragma unroll
            for (int nt = 0; nt < 2; nt++) {
                acc[mt][nt] = __builtin_amdgcn_mfma_f32_16x16x32_bf16(al[mt], bh[nt], acc[mt][nt], 0, 0, 0);
                acc[mt][nt] = __builtin_amdgcn_mfma_f32_16x16x32_bf16(ah[mt], bl[nt], acc[mt][nt], 0, 0, 0);
                acc[mt][nt] = __builtin_amdgcn_mfma_f32_16x16x32_bf16(ah[mt], bh[nt], acc[mt][nt], 0, 0, 0);
            }
        __syncthreads();
    }

#pragma unroll
    for (int nt = 0; nt < 2; nt++) {
        const int col = colStart + wc*32 + nt*16 + col16;
        const float bns = bias[col];
#pragma unroll
        for (int mt = 0; mt < 4; mt++)
#pragma unroll
            for (int r = 0; r < 4; r++) {
                const int row = rowStart + wr*64 + mt*16 + quad*4 + r;
                out[(size_t)row * Nc + col] = acc[mt][nt][r] + bns;
            }
    }
}

// ---------------------------------------------------------------------------
// Wave-parallel exact top-k: one wave per row (4 rows / block).
// 16x butterfly argmax-extract over 192 candidates (3/lane, registers only),
// fp64 re-check of those 16, 4th-largest threshold, neighbor write.
// No LDS, no __syncthreads, no dynamic-index arrays.
// ---------------------------------------------------------------------------
__global__ __launch_bounds__(256) void topk_merge(
    const float* __restrict__ x,
    const float* __restrict__ cand_val, const int* __restrict__ cand_idx,
    int* __restrict__ nbr_idx, int* __restrict__ nbr_cnt,
    float* __restrict__ dinv_arr)
{
    const int wv = threadIdx.x >> 6, lane = threadIdx.x & 63;
    const int row = blockIdx.x * 4 + wv;

    const size_t cb = (size_t)row * NCAND;
    float lv0 = cand_val[cb + lane];
    float lv1 = cand_val[cb + 64 + lane];
    float lv2 = cand_val[cb + 128 + lane];
    int   gi0 = cand_idx[cb + lane];
    int   gi1 = cand_idx[cb + 64 + lane];
    int   gi2 = cand_idx[cb + 128 + lane];

    int tj[NCHK];
#pragma unroll
    for (int it = 0; it < NCHK; it++) {
        float bv = lv0; int bm = gi0;
        if (lv1 > bv || (lv1 == bv && gi1 < bm)) { bv = lv1; bm = gi1; }
        if (lv2 > bv || (lv2 == bv && gi2 < bm)) { bv = lv2; bm = gi2; }
#pragma unroll
        for (int off = 32; off; off >>= 1) {
            float ov = __shfl_xor(bv, off);
            int   om = __shfl_xor(bm, off);
            if (ov > bv || (ov == bv && om < bm)) { bv = ov; bm = om; }
        }
        tj[it] = bm;                  // all lanes agree
        if (bm == gi0)      lv0 = -1e30f;
        else if (bm == gi1) lv1 = -1e30f;
        else if (bm == gi2) lv2 = -1e30f;
    }

    // fp64 exact dots for the 16 candidates (kept in registers, all lanes)
    const float* xr = x + (size_t)row * C_;
    float xrv[8];
#pragma unroll
    for (int k = 0; k < 8; k++) xrv[k] = xr[lane + k*64];

    double dvr[NCHK];
#pragma unroll
    for (int c = 0; c < NCHK; c++) {
        const float* xj = x + (size_t)tj[c] * C_;
        double s = 0.0;
#pragma unroll
        for (int k = 0; k < 8; k++)
            s += (double)xrv[k] * (double)xj[lane + k*64];
#pragma unroll
        for (int off = 32; off; off >>= 1) s += __shfl_xor(s, off);
        dvr[c] = s;                   // butterfly -> every lane has the sum
    }

    // 4th largest of dvr[0..15] (branchless-ish, constant indices)
    double m0 = -1e300, m1 = -1e300, m2 = -1e300, m3 = -1e300;
#pragma unroll
    for (int c = 0; c < NCHK; c++) {
        double v = dvr[c];
        if (v > m3) {
            if (v > m0)      { m3 = m2; m2 = m1; m1 = m0; m0 = v; }
            else if (v > m1) { m3 = m2; m2 = m1; m1 = v; }
            else if (v > m2) { m3 = m2; m2 = v; }
            else               m3 = v;
        }
    }
    const double thr = m3;

    if (lane == 0) {
        int cnt = 0;
#pragma unroll
        for (int c = 0; c < NCHK; c++) {
            bool keep = dvr[c] >= thr;
            if (keep) nbr_idx[(size_t)row * MAXN + cnt] = tj[c];
            cnt += keep ? 1 : 0;
        }
        nbr_cnt[row]  = cnt;
        dinv_arr[row] = (float)(1.0 / sqrt((double)cnt));
    }
}

// ---------------------------------------------------------------------------
// z = u + dinv_i * sum_j dinv_j * v_j ; per-row BN over C ; relu(x + norm) ;
// emit h pre-split into bf16 hi/lo planes for the fc MFMA GEMM.
// ---------------------------------------------------------------------------
__global__ __launch_bounds__(256) void aggregate_bn(
    const float* __restrict__ x, const float* __restrict__ u,
    const float* __restrict__ v,
    const int* __restrict__ nbr_idx, const int* __restrict__ nbr_cnt,
    const float* __restrict__ dinv_arr,
    unsigned short* __restrict__ hh, unsigned short* __restrict__ hl)
{
    const int row = blockIdx.x;
    const int t = threadIdx.x;
    __shared__ int   s_nbr[MAXN];
    __shared__ float s_w[MAXN];
    __shared__ int   s_cnt;
    __shared__ float s_di;
    __shared__ float r1[4], r2[4];
    __shared__ float s_mean, s_istd;

    if (t == 0) { s_cnt = nbr_cnt[row]; s_di = dinv_arr[row]; }
    __syncthreads();
    const int cnt = s_cnt;
    if (t < cnt) {
        int j = nbr_idx[(size_t)row * MAXN + t];
        s_nbr[t] = j;
        s_w[t]   = dinv_arr[j];
    }
    __syncthreads();

    const float di = s_di;
    float z[2];
    float sum = 0.f, sumsq = 0.f;
#pragma unroll
    for (int e = 0; e < 2; e++) {
        const int c = t + e * 256;
        float s = 0.f;
        for (int m = 0; m < cnt; m++)
            s += s_w[m] * v[(size_t)s_nbr[m] * C_ + c];
        float zz = u[(size_t)row * C_ + c] + di * s;
        z[e] = zz;
        sum += zz; sumsq += zz * zz;
    }

    float a = sum, b = sumsq;
#pragma unroll
    for (int o = 32; o > 0; o >>= 1) { a += __shfl_down(a, o); b += __shfl_down(b, o); }
    const int wave = t >> 6, lane = t & 63;
    if (lane == 0) { r1[wave] = a; r2[wave] = b; }
    __syncthreads();
    if (t == 0) {
        float ta = r1[0] + r1[1] + r1[2] + r1[3];
        float tb = r2[0] + r2[1] + r2[2] + r2[3];
        float mean = ta / (float)C_;
        float var  = tb / (float)C_ - mean * mean;
        s_mean = mean;
        s_istd = 1.0f / sqrtf(var + EPSF);
    }
    __syncthreads();

    const float mean = s_mean, istd = s_istd;
#pragma unroll
    for (int e = 0; e < 2; e++) {
        const int c = t + e * 256;
        float hhv = fmaxf(x[(size_t)row * C_ + c] + (z[e] - mean) * istd, 0.f);
        unsigned short hb = f2bf(hhv);
        hh[(size_t)row * C_ + c] = hb;
        hl[(size_t)row * C_ + c] = f2bf(hhv - bf2f(hb));
    }
}

// ---------------------------------------------------------------------------
extern "C" void kernel_launch(void* const* d_in, const int* in_sizes, int n_in,
                              void* d_out, int out_size, void* d_ws, size_t ws_size,
                              hipStream_t stream)
{
    const float* x    = (const float*)d_in[0];
    const float* U_w  = (const float*)d_in[1];
    const float* U_b  = (const float*)d_in[2];
    const float* V_w  = (const float*)d_in[3];
    const float* V_b  = (const float*)d_in[4];
    const float* fc_w = (const float*)d_in[5];
    const float* fc_b = (const float*)d_in[6];
    float* out = (float*)d_out;

    char* p = (char*)d_ws;
    auto alloc = [&](size_t bytes) { char* r = p; p += (bytes + 255) & ~(size_t)255; return r; };
    unsigned short* xh = (unsigned short*)alloc((size_t)N_ * C_ * 2);
    unsigned short* xl = (unsigned short*)alloc((size_t)N_ * C_ * 2);
    unsigned short* uh = (unsigned short*)alloc((size_t)C_ * C_ * 2);
    unsigned short* ul = (unsigned short*)alloc((size_t)C_ * C_ * 2);
    unsigned short* vh = (unsigned short*)alloc((size_t)C_ * C_ * 2);
    unsigned short* vl = (unsigned short*)alloc((size_t)C_ * C_ * 2);
    unsigned short* fh = (unsigned short*)alloc((size_t)OUT_ * C_ * 2);
    unsigned short* fl = (unsigned short*)alloc((size_t)OUT_ * C_ * 2);
    unsigned short* hh = (unsigned short*)alloc((size_t)N_ * C_ * 2);
    unsigned short* hl = (unsigned short*)alloc((size_t)N_ * C_ * 2);
    float* u_buf    = (float*)alloc((size_t)N_ * C_ * 4);
    float* v_buf    = (float*)alloc((size_t)N_ * C_ * 4);
    float* cand_val = (float*)alloc((size_t)N_ * NCAND * 4);
    int*   cand_idx = (int*)  alloc((size_t)N_ * NCAND * 4);
    int*   nbr_idx  = (int*)  alloc((size_t)N_ * MAXN * 4);
    int*   nbr_cnt  = (int*)  alloc((size_t)N_ * 4);
    float* dinv     = (float*)alloc((size_t)N_ * 4);

    hipLaunchKernelGGL(split_bf16_kernel, dim3(N_*C_/4/256), dim3(256), 0, stream, x, xh, xl, N_*C_/4);
    hipLaunchKernelGGL(split_bf16_kernel, dim3(C_*C_/4/256), dim3(256), 0, stream, U_w, uh, ul, C_*C_/4);
    hipLaunchKernelGGL(split_bf16_kernel, dim3(C_*C_/4/256), dim3(256), 0, stream, V_w, vh, vl, C_*C_/4);
    hipLaunchKernelGGL(split_bf16_kernel, dim3(OUT_*C_/4/256), dim3(256), 0, stream, fc_w, fh, fl, OUT_*C_/4);

    hipLaunchKernelGGL(syrk_topk_mfma, dim3(N_/128, N_/128), dim3(256), 0, stream,
                       xh, cand_val, cand_idx);

    hipLaunchKernelGGL(topk_merge, dim3(N_/4), dim3(256), 0, stream,
                       x, cand_val, cand_idx, nbr_idx, nbr_cnt, dinv);

    hipLaunchKernelGGL(gemm_split, dim3(C_/64, N_/128), dim3(256), 0, stream,
                       xh, xl, uh, ul, U_b, u_buf, C_);
    hipLaunchKernelGGL(gemm_split, dim3(C_/64, N_/128), dim3(256), 0, stream,
                       xh, xl, vh, vl, V_b, v_buf, C_);

    hipLaunchKernelGGL(aggregate_bn, dim3(N_), dim3(256), 0, stream,
                       x, u_buf, v_buf, nbr_idx, nbr_cnt, dinv, hh, hl);

    hipLaunchKernelGGL(gemm_split, dim3(OUT_/64, N_/128), dim3(256), 0, stream,
                       hh, hl, fh, fl, fc_b, out, OUT_);
}

// Round 4
// 312.574 us; speedup vs baseline: 2.1170x; 1.1546x over previous
//
#include <hip/hip_runtime.h>
#include <cstddef>
#include <cstdint>

#define N_    4096
#define C_    512
#define OUT_  256
#define EPSF  1e-5f

#define NSTRIPE 32            // N/128 stripes
#define NSEL   6              // top-6 kept per 128-tile side (bf16 safety margin)
#define NCAND  (NSTRIPE*NSEL) // 192 candidates per row (32 slots x 6)
#define NCHK   16             // candidates re-checked in fp64
#define MAXN   16             // max stored neighbors

typedef __attribute__((ext_vector_type(8))) short short8;
typedef __attribute__((ext_vector_type(4))) float f32x4;

typedef unsigned int u32;
typedef const u32 __attribute__((address_space(1)))* gptr_t;
typedef u32 __attribute__((address_space(3)))* lptr_t;

// Async global->LDS DMA, 16 B/lane. LDS dst = wave-uniform base + lane*16.
__device__ __forceinline__ void dma16(const unsigned short* g, unsigned short* l) {
    __builtin_amdgcn_global_load_lds((gptr_t)(uintptr_t)g, (lptr_t)(uintptr_t)l, 16, 0, 0);
}

__device__ __forceinline__ unsigned short f2bf(float f) {
    union { float f; unsigned u; } v; v.f = f;
    return (unsigned short)((v.u + 0x7FFFu + ((v.u >> 16) & 1u)) >> 16);
}
__device__ __forceinline__ float bf2f(unsigned short h) {
    union { unsigned u; float f; } v; v.u = ((unsigned)h) << 16;
    return v.f;
}

// Branchless constant-index top-6 insert (descending) — stays in VGPRs.
struct Top6 { float v[NSEL]; int i[NSEL]; };
__device__ __forceinline__ void top6_init(Top6& s) {
#pragma unroll
    for (int m = 0; m < NSEL; m++) { s.v[m] = -1e30f; s.i[m] = -1; }
}
__device__ __forceinline__ void top6_insert(Top6& s, float vv, int gc) {
    if (vv <= s.v[5]) return;
    bool g0 = vv > s.v[0], g1 = vv > s.v[1], g2 = vv > s.v[2],
         g3 = vv > s.v[3], g4 = vv > s.v[4];
    s.v[5] = g4 ? s.v[4] : vv;                  s.i[5] = g4 ? s.i[4] : gc;
    s.v[4] = g3 ? s.v[3] : (g4 ? vv : s.v[4]);  s.i[4] = g3 ? s.i[3] : (g4 ? gc : s.i[4]);
    s.v[3] = g2 ? s.v[2] : (g3 ? vv : s.v[3]);  s.i[3] = g2 ? s.i[2] : (g3 ? gc : s.i[3]);
    s.v[2] = g1 ? s.v[1] : (g2 ? vv : s.v[2]);  s.i[2] = g1 ? s.i[1] : (g2 ? gc : s.i[2]);
    s.v[1] = g0 ? s.v[0] : (g1 ? vv : s.v[1]);  s.i[1] = g0 ? s.i[0] : (g1 ? gc : s.i[1]);
    s.v[0] = g0 ? vv : s.v[0];                  s.i[0] = g0 ? gc : s.i[0];
}

// ---------------------------------------------------------------------------
// Split each fp32 into hi/lo bf16 planes: x ~= hi + lo.
// ---------------------------------------------------------------------------
__global__ __launch_bounds__(256) void split_bf16_kernel(
    const float* __restrict__ src, unsigned short* __restrict__ hi,
    unsigned short* __restrict__ lo, int n4)
{
    int i = blockIdx.x * 256 + threadIdx.x;
    if (i >= n4) return;
    float4 f = ((const float4*)src)[i];
    ushort4 h, l;
    h.x = f2bf(f.x); l.x = f2bf(f.x - bf2f(h.x));
    h.y = f2bf(f.y); l.y = f2bf(f.y - bf2f(h.y));
    h.z = f2bf(f.z); l.z = f2bf(f.z - bf2f(h.z));
    h.w = f2bf(f.w); l.w = f2bf(f.w - bf2f(h.w));
    ((ushort4*)hi)[i] = h;
    ((ushort4*)lo)[i] = l;
}

// ---------------------------------------------------------------------------
// Triangle MFMA syrk + fused two-sided top-6.
// Grid: 528 blocks = upper-triangle (bi<=bj) of 32x32 stripe pairs.
// K-loop: global_load_lds (16B) -> LDS (no VGPR round-trip), 2 barriers/iter.
// Epilogue: bf16 stile (stride 66); row-side top6 -> slot bj, col-side top6
// -> slot bi (skipped on diagonal). Every row gets all 32 slots exactly once.
// ---------------------------------------------------------------------------
#define SBK 64   // K-tile width (bf16 elems); row = 128 B; NO padding (DMA)

union SyrkSmem {
    struct { unsigned short A[128 * SBK]; unsigned short B[128 * SBK]; } stg;   // 32768 B
    struct { unsigned short stile[128 * 66]; float pv[256 * NSEL]; int pi[256 * NSEL]; } sel; // 29184 B
};

__global__ __launch_bounds__(256) void syrk_topk_mfma(
    const unsigned short* __restrict__ xb,
    float* __restrict__ cand_val, int* __restrict__ cand_idx)
{
    __shared__ SyrkSmem sm;
    const int t = threadIdx.x;
    const int lane = t & 63, w = t >> 6;
    const int wr = w >> 1, wc = w & 1;
    const int col16 = lane & 15, quad = lane >> 4;
    const int ln8 = lane >> 3, lc8 = (lane & 7) * 8;

    // triangle decode: blockIdx.x -> (bi, bj), bi <= bj
    int bi = 0, rem = blockIdx.x;
    while (rem >= NSTRIPE - bi) { rem -= NSTRIPE - bi; bi++; }
    const int bj = bi + rem;
    const int rowStart = bi * 128, colStart = bj * 128;

    f32x4 acc[4][4] = {};

    for (int k0 = 0; k0 < C_; k0 += SBK) {
        // wave w stages rows [w*32, w*32+32) of A and B: 4+4 DMA instrs
#pragma unroll
        for (int i = 0; i < 4; i++) {
            const int r8 = w * 32 + i * 8;   // 8 rows per 1 KB instr
            dma16(xb + (size_t)(rowStart + r8 + ln8) * C_ + k0 + lc8, &sm.stg.A[r8 * SBK]);
            dma16(xb + (size_t)(colStart + r8 + ln8) * C_ + k0 + lc8, &sm.stg.B[r8 * SBK]);
        }
        __syncthreads();   // vmcnt drained -> tiles visible
#pragma unroll
        for (int ks = 0; ks < 2; ks++) {
            short8 af[4], bfr[4];
#pragma unroll
            for (int mt = 0; mt < 4; mt++)
                af[mt] = *(const short8*)&sm.stg.A[(wr*64 + mt*16 + col16) * SBK + ks*32 + quad*8];
#pragma unroll
            for (int nt = 0; nt < 4; nt++)
                bfr[nt] = *(const short8*)&sm.stg.B[(wc*64 + nt*16 + col16) * SBK + ks*32 + quad*8];
#pragma unroll
            for (int mt = 0; mt < 4; mt++)
#pragma unroll
                for (int nt = 0; nt < 4; nt++)
                    acc[mt][nt] = __builtin_amdgcn_mfma_f32_16x16x32_bf16(
                        af[mt], bfr[nt], acc[mt][nt], 0, 0, 0);
        }
        __syncthreads();   // compute done before next DMA overwrites
    }

    // ---- fused two-sided selection over two 128x64 half-tiles ----
    Top6 tkRow; top6_init(tkRow);
    const int srow = t >> 1, ss = t & 1;    // row-scan: 2 thr/row, 32 cols each
    const int scol = t >> 2, seg = t & 3;   // col-scan: 4 thr/col, 32 rows each

    for (int p = 0; p < 2; p++) {
        if (wc == p) {
#pragma unroll
            for (int mt = 0; mt < 4; mt++)
#pragma unroll
                for (int nt = 0; nt < 4; nt++)
#pragma unroll
                    for (int r = 0; r < 4; r++)
                        sm.sel.stile[(wr*64 + mt*16 + quad*4 + r) * 66 + nt*16 + col16] =
                            f2bf(acc[mt][nt][r]);
        }
        __syncthreads();
        // row side (persistent across halves)
#pragma unroll
        for (int c = 0; c < 32; c++) {
            float vv = bf2f(sm.sel.stile[srow * 66 + ss*32 + c]);
            top6_insert(tkRow, vv, colStart + p*64 + ss*32 + c);
        }
        // col side (per half): interleaved rows to spread LDS banks
        Top6 tkCol; top6_init(tkCol);
#pragma unroll
        for (int it = 0; it < 32; it++) {
            const int r = it*4 + seg;
            float vv = bf2f(sm.sel.stile[r * 66 + scol]);
            top6_insert(tkCol, vv, rowStart + r);
        }
#pragma unroll
        for (int m = 0; m < NSEL; m++) { sm.sel.pv[t*NSEL+m] = tkCol.v[m]; sm.sel.pi[t*NSEL+m] = tkCol.i[m]; }
        __syncthreads();
        if (bi != bj && t < 64) {
            Top6 mk; top6_init(mk);
            for (int s4 = 0; s4 < 4; s4++)
#pragma unroll
                for (int m2 = 0; m2 < NSEL; m2++)
                    top6_insert(mk, sm.sel.pv[(t*4+s4)*NSEL+m2], sm.sel.pi[(t*4+s4)*NSEL+m2]);
            const size_t base = (size_t)(colStart + p*64 + t) * NCAND + bi * NSEL;
#pragma unroll
            for (int m = 0; m < NSEL; m++) { cand_val[base+m] = mk.v[m]; cand_idx[base+m] = mk.i[m]; }
        }
        __syncthreads();   // pv/pi + stile free for next half
    }

    // row-side merge (2 partials per row)
#pragma unroll
    for (int m = 0; m < NSEL; m++) { sm.sel.pv[t*NSEL+m] = tkRow.v[m]; sm.sel.pi[t*NSEL+m] = tkRow.i[m]; }
    __syncthreads();
    if (t < 128) {
        Top6 mk; top6_init(mk);
        for (int s2 = 0; s2 < 2; s2++)
#pragma unroll
            for (int m2 = 0; m2 < NSEL; m2++)
                top6_insert(mk, sm.sel.pv[(t*2+s2)*NSEL+m2], sm.sel.pi[(t*2+s2)*NSEL+m2]);
        const size_t base = (size_t)(rowStart + t) * NCAND + bj * NSEL;
#pragma unroll
        for (int m = 0; m < NSEL; m++) { cand_val[base+m] = mk.v[m]; cand_idx[base+m] = mk.i[m]; }
    }
}

// ---------------------------------------------------------------------------
// Split-bf16 GEMM via global_load_lds: out[M,Nc] = (Ah+Al)@(Bh+Bl)^T + bias.
// Tile 128x64, BK=32, 4 waves (each 64x32), 3 MFMAs per tile pair.
// bias: col < SP ? bias0[col] : bias1[col-SP]  (lets U/V share one GEMM).
// ---------------------------------------------------------------------------
__global__ __launch_bounds__(256) void gemm_split(
    const unsigned short* __restrict__ Ah, const unsigned short* __restrict__ Al,
    const unsigned short* __restrict__ Bh, const unsigned short* __restrict__ Bl,
    const float* __restrict__ bias0, const float* __restrict__ bias1, int SP,
    float* __restrict__ out, int Nc)
{
    __shared__ unsigned short sAh[128*32], sAl[128*32], sBh[64*32], sBl[64*32]; // 24 KB
    const int t = threadIdx.x;
    const int lane = t & 63, w = t >> 6;
    const int wr = w >> 1, wc = w & 1;
    const int col16 = lane & 15, quad = lane >> 4;
    const int ln4 = lane >> 2, lc4 = (lane & 3) * 8;   // 16 rows x 32 elems per 1 KB instr
    const int rowStart = blockIdx.y * 128, colStart = blockIdx.x * 64;

    f32x4 acc[4][2] = {};

    for (int k0 = 0; k0 < C_; k0 += 32) {
        // 24 DMA units of 1 KB (16 rows of 32 bf16): Ah 8, Al 8, Bh 4, Bl 4
#pragma unroll
        for (int j = 0; j < 6; j++) {
            const int u = w * 6 + j;
            const unsigned short* gs; unsigned short* ld;
            if (u < 8)       { const int rb = u*16;      gs = Ah + (size_t)(rowStart + rb + ln4) * C_; ld = sAh + rb*32; }
            else if (u < 16) { const int rb = (u-8)*16;  gs = Al + (size_t)(rowStart + rb + ln4) * C_; ld = sAl + rb*32; }
            else if (u < 20) { const int rb = (u-16)*16; gs = Bh + (size_t)(colStart + rb + ln4) * C_; ld = sBh + rb*32; }
            else             { const int rb = (u-20)*16; gs = Bl + (size_t)(colStart + rb + ln4) * C_; ld = sBl + rb*32; }
            dma16(gs + k0 + lc4, ld);
        }
        __syncthreads();

        short8 ah[4], al4[4], bh2[2], bl2[2];
#pragma unroll
        for (int mt = 0; mt < 4; mt++) {
            const int ro = (wr*64 + mt*16 + col16) * 32 + quad*8;
            ah[mt]  = *(const short8*)&sAh[ro];
            al4[mt] = *(const short8*)&sAl[ro];
        }
#pragma unroll
        for (int nt = 0; nt < 2; nt++) {
            const int ro = (wc*32 + nt*16 + col16) * 32 + quad*8;
            bh2[nt] = *(const short8*)&sBh[ro];
            bl2[nt] = *(const short8*)&sBl[ro];
        }
#pragma unroll
        for (int mt = 0; mt < 4; mt++)
#pragma unroll
            for (int nt = 0; nt < 2; nt++) {
                acc[mt][nt] = __builtin_amdgcn_mfma_f32_16x16x32_bf16(al4[mt], bh2[nt], acc[mt][nt], 0, 0, 0);
                acc[mt][nt] = __builtin_amdgcn_mfma_f32_16x16x32_bf16(ah[mt],  bl2[nt], acc[mt][nt], 0, 0, 0);
                acc[mt][nt] = __builtin_amdgcn_mfma_f32_16x16x32_bf16(ah[mt],  bh2[nt], acc[mt][nt], 0, 0, 0);
            }
        __syncthreads();
    }

#pragma unroll
    for (int nt = 0; nt < 2; nt++) {
        const int col = colStart + wc*32 + nt*16 + col16;
        const float bns = (col < SP) ? bias0[col] : bias1[col - SP];
#pragma unroll
        for (int mt = 0; mt < 4; mt++)
#pragma unroll
            for (int r = 0; r < 4; r++) {
                const int row = rowStart + wr*64 + mt*16 + quad*4 + r;
                out[(size_t)row * Nc + col] = acc[mt][nt][r] + bns;
            }
    }
}

// ---------------------------------------------------------------------------
// Wave-parallel exact top-k (one wave/row): 16x butterfly argmax-extract over
// 192 candidates, fp64 re-check, 4th-largest threshold, neighbor write.
// ---------------------------------------------------------------------------
__global__ __launch_bounds__(256) void topk_merge(
    const float* __restrict__ x,
    const float* __restrict__ cand_val, const int* __restrict__ cand_idx,
    int* __restrict__ nbr_idx, int* __restrict__ nbr_cnt,
    float* __restrict__ dinv_arr)
{
    const int wv = threadIdx.x >> 6, lane = threadIdx.x & 63;
    const int row = blockIdx.x * 4 + wv;

    const size_t cb = (size_t)row * NCAND;
    float lv0 = cand_val[cb + lane];
    float lv1 = cand_val[cb + 64 + lane];
    float lv2 = cand_val[cb + 128 + lane];
    int   gi0 = cand_idx[cb + lane];
    int   gi1 = cand_idx[cb + 64 + lane];
    int   gi2 = cand_idx[cb + 128 + lane];

    int tj[NCHK];
#pragma unroll
    for (int it = 0; it < NCHK; it++) {
        float bv = lv0; int bm = gi0;
        if (lv1 > bv || (lv1 == bv && gi1 < bm)) { bv = lv1; bm = gi1; }
        if (lv2 > bv || (lv2 == bv && gi2 < bm)) { bv = lv2; bm = gi2; }
#pragma unroll
        for (int off = 32; off; off >>= 1) {
            float ov = __shfl_xor(bv, off);
            int   om = __shfl_xor(bm, off);
            if (ov > bv || (ov == bv && om < bm)) { bv = ov; bm = om; }
        }
        tj[it] = bm;
        if (bm == gi0)      lv0 = -1e30f;
        else if (bm == gi1) lv1 = -1e30f;
        else if (bm == gi2) lv2 = -1e30f;
    }

    const float* xr = x + (size_t)row * C_;
    float xrv[8];
#pragma unroll
    for (int k = 0; k < 8; k++) xrv[k] = xr[lane + k*64];

    double dvr[NCHK];
#pragma unroll
    for (int c = 0; c < NCHK; c++) {
        const float* xj = x + (size_t)tj[c] * C_;
        double s = 0.0;
#pragma unroll
        for (int k = 0; k < 8; k++)
            s += (double)xrv[k] * (double)xj[lane + k*64];
#pragma unroll
        for (int off = 32; off; off >>= 1) s += __shfl_xor(s, off);
        dvr[c] = s;
    }

    double m0 = -1e300, m1 = -1e300, m2 = -1e300, m3 = -1e300;
#pragma unroll
    for (int c = 0; c < NCHK; c++) {
        double v = dvr[c];
        if (v > m3) {
            if (v > m0)      { m3 = m2; m2 = m1; m1 = m0; m0 = v; }
            else if (v > m1) { m3 = m2; m2 = m1; m1 = v; }
            else if (v > m2) { m3 = m2; m2 = v; }
            else               m3 = v;
        }
    }
    const double thr = m3;

    if (lane == 0) {
        int cnt = 0;
#pragma unroll
        for (int c = 0; c < NCHK; c++) {
            bool keep = dvr[c] >= thr;
            if (keep) nbr_idx[(size_t)row * MAXN + cnt] = tj[c];
            cnt += keep ? 1 : 0;
        }
        nbr_cnt[row]  = cnt;
        dinv_arr[row] = (float)(1.0 / sqrt((double)cnt));
    }
}

// ---------------------------------------------------------------------------
// z = u + dinv_i * sum_j dinv_j * v_j ; per-row BN over C ; relu(x + norm).
// zuv[N][1024]: cols 0..511 = u-part, 512..1023 = v-part (fused U/V GEMM).
// Emits h split into bf16 hi/lo planes for the fc GEMM.
// ---------------------------------------------------------------------------
__global__ __launch_bounds__(256) void aggregate_bn(
    const float* __restrict__ x, const float* __restrict__ zuv,
    const int* __restrict__ nbr_idx, const int* __restrict__ nbr_cnt,
    const float* __restrict__ dinv_arr,
    unsigned short* __restrict__ hh, unsigned short* __restrict__ hl)
{
    const int row = blockIdx.x;
    const int t = threadIdx.x;
    __shared__ int   s_nbr[MAXN];
    __shared__ float s_w[MAXN];
    __shared__ int   s_cnt;
    __shared__ float s_di;
    __shared__ float r1[4], r2[4];
    __shared__ float s_mean, s_istd;

    if (t == 0) { s_cnt = nbr_cnt[row]; s_di = dinv_arr[row]; }
    __syncthreads();
    const int cnt = s_cnt;
    if (t < cnt) {
        int j = nbr_idx[(size_t)row * MAXN + t];
        s_nbr[t] = j;
        s_w[t]   = dinv_arr[j];
    }
    __syncthreads();

    const float di = s_di;
    float z[2];
    float sum = 0.f, sumsq = 0.f;
#pragma unroll
    for (int e = 0; e < 2; e++) {
        const int c = t + e * 256;
        float s = 0.f;
        for (int m = 0; m < cnt; m++)
            s += s_w[m] * zuv[(size_t)s_nbr[m] * 1024 + 512 + c];
        float zz = zuv[(size_t)row * 1024 + c] + di * s;
        z[e] = zz;
        sum += zz; sumsq += zz * zz;
    }

    float a = sum, b = sumsq;
#pragma unroll
    for (int o = 32; o > 0; o >>= 1) { a += __shfl_down(a, o); b += __shfl_down(b, o); }
    const int wave = t >> 6, lane = t & 63;
    if (lane == 0) { r1[wave] = a; r2[wave] = b; }
    __syncthreads();
    if (t == 0) {
        float ta = r1[0] + r1[1] + r1[2] + r1[3];
        float tb = r2[0] + r2[1] + r2[2] + r2[3];
        float mean = ta / (float)C_;
        float var  = tb / (float)C_ - mean * mean;
        s_mean = mean;
        s_istd = 1.0f / sqrtf(var + EPSF);
    }
    __syncthreads();

    const float mean = s_mean, istd = s_istd;
#pragma unroll
    for (int e = 0; e < 2; e++) {
        const int c = t + e * 256;
        float hhv = fmaxf(x[(size_t)row * C_ + c] + (z[e] - mean) * istd, 0.f);
        unsigned short hb = f2bf(hhv);
        hh[(size_t)row * C_ + c] = hb;
        hl[(size_t)row * C_ + c] = f2bf(hhv - bf2f(hb));
    }
}

// ---------------------------------------------------------------------------
extern "C" void kernel_launch(void* const* d_in, const int* in_sizes, int n_in,
                              void* d_out, int out_size, void* d_ws, size_t ws_size,
                              hipStream_t stream)
{
    const float* x    = (const float*)d_in[0];
    const float* U_w  = (const float*)d_in[1];
    const float* U_b  = (const float*)d_in[2];
    const float* V_w  = (const float*)d_in[3];
    const float* V_b  = (const float*)d_in[4];
    const float* fc_w = (const float*)d_in[5];
    const float* fc_b = (const float*)d_in[6];
    float* out = (float*)d_out;

    char* p = (char*)d_ws;
    auto alloc = [&](size_t bytes) { char* r = p; p += (bytes + 255) & ~(size_t)255; return r; };
    unsigned short* xh = (unsigned short*)alloc((size_t)N_ * C_ * 2);
    unsigned short* xl = (unsigned short*)alloc((size_t)N_ * C_ * 2);
    unsigned short* wh = (unsigned short*)alloc((size_t)1024 * C_ * 2);   // [U_w; V_w] hi
    unsigned short* wl = (unsigned short*)alloc((size_t)1024 * C_ * 2);   // [U_w; V_w] lo
    unsigned short* fh = (unsigned short*)alloc((size_t)OUT_ * C_ * 2);
    unsigned short* fl = (unsigned short*)alloc((size_t)OUT_ * C_ * 2);
    unsigned short* hh = (unsigned short*)alloc((size_t)N_ * C_ * 2);
    unsigned short* hl = (unsigned short*)alloc((size_t)N_ * C_ * 2);
    float* zuv      = (float*)alloc((size_t)N_ * 1024 * 4);               // u | v
    float* cand_val = (float*)alloc((size_t)N_ * NCAND * 4);
    int*   cand_idx = (int*)  alloc((size_t)N_ * NCAND * 4);
    int*   nbr_idx  = (int*)  alloc((size_t)N_ * MAXN * 4);
    int*   nbr_cnt  = (int*)  alloc((size_t)N_ * 4);
    float* dinv     = (float*)alloc((size_t)N_ * 4);

    // fp32 -> bf16 hi/lo planes (V_w lands at rows 512..1023 of w-concat)
    hipLaunchKernelGGL(split_bf16_kernel, dim3(N_*C_/4/256), dim3(256), 0, stream, x, xh, xl, N_*C_/4);
    hipLaunchKernelGGL(split_bf16_kernel, dim3(C_*C_/4/256), dim3(256), 0, stream, U_w, wh, wl, C_*C_/4);
    hipLaunchKernelGGL(split_bf16_kernel, dim3(C_*C_/4/256), dim3(256), 0, stream, V_w, wh + (size_t)C_*C_, wl + (size_t)C_*C_, C_*C_/4);
    hipLaunchKernelGGL(split_bf16_kernel, dim3(OUT_*C_/4/256), dim3(256), 0, stream, fc_w, fh, fl, OUT_*C_/4);

    // similarity (triangle) + two-sided per-tile top-6 candidates
    hipLaunchKernelGGL(syrk_topk_mfma, dim3(NSTRIPE*(NSTRIPE+1)/2), dim3(256), 0, stream,
                       xh, cand_val, cand_idx);

    // exact merge -> neighbors, deg, dinv
    hipLaunchKernelGGL(topk_merge, dim3(N_/4), dim3(256), 0, stream,
                       x, cand_val, cand_idx, nbr_idx, nbr_cnt, dinv);

    // fused [u|v] = x @ [U_w;V_w]^T + [U_b|V_b]
    hipLaunchKernelGGL(gemm_split, dim3(1024/64, N_/128), dim3(256), 0, stream,
                       xh, xl, wh, wl, U_b, V_b, 512, zuv, 1024);

    // aggregate + BN + relu -> h (bf16 split)
    hipLaunchKernelGGL(aggregate_bn, dim3(N_), dim3(256), 0, stream,
                       x, zuv, nbr_idx, nbr_cnt, dinv, hh, hl);

    // out = h @ fc_w.T + fc_b
    hipLaunchKernelGGL(gemm_split, dim3(OUT_/64, N_/128), dim3(256), 0, stream,
                       hh, hl, fh, fl, fc_b, fc_b, 1 << 30, out, OUT_);
}

// Round 5
// 249.241 us; speedup vs baseline: 2.6550x; 1.2541x over previous
//
#include <hip/hip_runtime.h>
#include <cstddef>
#include <cstdint>

#define N_    4096
#define C_    512
#define OUT_  256
#define EPSF  1e-5f

#define NSTRIPE 32            // N/128 stripes
#define NSEL   6              // top-6 kept per 128-tile side (bf16 safety margin)
#define NCAND  (NSTRIPE*NSEL) // 192 candidates per row (32 slots x 6)
#define NCHK   16             // candidates re-checked in fp64
#define MAXN   16             // max stored neighbors

typedef __attribute__((ext_vector_type(8))) short short8;
typedef __attribute__((ext_vector_type(4))) float f32x4;

typedef unsigned int u32;
typedef const u32 __attribute__((address_space(1)))* gptr_t;
typedef u32 __attribute__((address_space(3)))* lptr_t;

// Async global->LDS DMA, 16 B/lane. LDS dst = wave-uniform base + lane*16.
__device__ __forceinline__ void dma16(const unsigned short* g, unsigned short* l) {
    __builtin_amdgcn_global_load_lds((gptr_t)(uintptr_t)g, (lptr_t)(uintptr_t)l, 16, 0, 0);
}

__device__ __forceinline__ unsigned short f2bf(float f) {
    union { float f; unsigned u; } v; v.f = f;
    return (unsigned short)((v.u + 0x7FFFu + ((v.u >> 16) & 1u)) >> 16);
}
__device__ __forceinline__ float bf2f(unsigned short h) {
    union { unsigned u; float f; } v; v.u = ((unsigned)h) << 16;
    return v.f;
}

// Branchless constant-index top-6 insert (descending) — stays in VGPRs.
struct Top6 { float v[NSEL]; int i[NSEL]; };
__device__ __forceinline__ void top6_init(Top6& s) {
#pragma unroll
    for (int m = 0; m < NSEL; m++) { s.v[m] = -1e30f; s.i[m] = -1; }
}
__device__ __forceinline__ void top6_insert(Top6& s, float vv, int gc) {
    if (vv <= s.v[5]) return;
    bool g0 = vv > s.v[0], g1 = vv > s.v[1], g2 = vv > s.v[2],
         g3 = vv > s.v[3], g4 = vv > s.v[4];
    s.v[5] = g4 ? s.v[4] : vv;                  s.i[5] = g4 ? s.i[4] : gc;
    s.v[4] = g3 ? s.v[3] : (g4 ? vv : s.v[4]);  s.i[4] = g3 ? s.i[3] : (g4 ? gc : s.i[4]);
    s.v[3] = g2 ? s.v[2] : (g3 ? vv : s.v[3]);  s.i[3] = g2 ? s.i[2] : (g3 ? gc : s.i[3]);
    s.v[2] = g1 ? s.v[1] : (g2 ? vv : s.v[2]);  s.i[2] = g1 ? s.i[1] : (g2 ? gc : s.i[2]);
    s.v[1] = g0 ? s.v[0] : (g1 ? vv : s.v[1]);  s.i[1] = g0 ? s.i[0] : (g1 ? gc : s.i[1]);
    s.v[0] = g0 ? vv : s.v[0];                  s.i[0] = g0 ? gc : s.i[0];
}

// ---------------------------------------------------------------------------
// Split each fp32 into hi/lo bf16 planes: x ~= hi + lo.
// ---------------------------------------------------------------------------
__global__ __launch_bounds__(256) void split_bf16_kernel(
    const float* __restrict__ src, unsigned short* __restrict__ hi,
    unsigned short* __restrict__ lo, int n4)
{
    int i = blockIdx.x * 256 + threadIdx.x;
    if (i >= n4) return;
    float4 f = ((const float4*)src)[i];
    ushort4 h, l;
    h.x = f2bf(f.x); l.x = f2bf(f.x - bf2f(h.x));
    h.y = f2bf(f.y); l.y = f2bf(f.y - bf2f(h.y));
    h.z = f2bf(f.z); l.z = f2bf(f.z - bf2f(h.z));
    h.w = f2bf(f.w); l.w = f2bf(f.w - bf2f(h.w));
    ((ushort4*)hi)[i] = h;
    ((ushort4*)lo)[i] = l;
}

// ---------------------------------------------------------------------------
// Triangle MFMA syrk + fused two-sided top-6, XOR-swizzled LDS.
// LDS row = 64 bf16 = 8 chunks of 16 B, no padding (DMA constraint).
// Physical chunk p of row r holds GLOBAL chunk p ^ (r&7); fragment reads use
// physical chunk (ks*4+quad) ^ (row&7) -> all 8 bank-quartets hit, 2 lanes
// each = conflict-free (m136: 2-way is free; unswizzled was 16-way).
// ---------------------------------------------------------------------------
#define SBK 64

union SyrkSmem {
    struct { unsigned short A[128 * SBK]; unsigned short B[128 * SBK]; } stg;   // 32768 B
    struct { float stile[128 * 65]; float pv[256 * NSEL]; int pi[256 * NSEL]; } sel; // 45568 B
};

__global__ __launch_bounds__(256) void syrk_topk_mfma(
    const unsigned short* __restrict__ xb,
    float* __restrict__ cand_val, int* __restrict__ cand_idx)
{
    __shared__ SyrkSmem sm;
    const int t = threadIdx.x;
    const int lane = t & 63, w = t >> 6;
    const int wr = w >> 1, wc = w & 1;
    const int col16 = lane & 15, quad = lane >> 4;
    const int ln8 = lane >> 3;
    const int csw = ((lane & 7) ^ ln8) * 8;   // swizzled global chunk offset (elems)

    // triangle decode: blockIdx.x -> (bi, bj), bi <= bj
    int bi = 0, rem = blockIdx.x;
    while (rem >= NSTRIPE - bi) { rem -= NSTRIPE - bi; bi++; }
    const int bj = bi + rem;
    const int rowStart = bi * 128, colStart = bj * 128;

    f32x4 acc[4][4] = {};

    for (int k0 = 0; k0 < C_; k0 += SBK) {
#pragma unroll
        for (int i = 0; i < 4; i++) {
            const int r8 = w * 32 + i * 8;   // 8 rows per 1 KB DMA
            dma16(xb + (size_t)(rowStart + r8 + ln8) * C_ + k0 + csw, &sm.stg.A[r8 * SBK]);
            dma16(xb + (size_t)(colStart + r8 + ln8) * C_ + k0 + csw, &sm.stg.B[r8 * SBK]);
        }
        __syncthreads();
#pragma unroll
        for (int ks = 0; ks < 2; ks++) {
            short8 af[4], bfr[4];
#pragma unroll
            for (int mt = 0; mt < 4; mt++) {
                const int r = wr*64 + mt*16 + col16;
                af[mt] = *(const short8*)&sm.stg.A[r * SBK + (((ks*4 + quad) ^ (r & 7)) * 8)];
            }
#pragma unroll
            for (int nt = 0; nt < 4; nt++) {
                const int r = wc*64 + nt*16 + col16;
                bfr[nt] = *(const short8*)&sm.stg.B[r * SBK + (((ks*4 + quad) ^ (r & 7)) * 8)];
            }
#pragma unroll
            for (int mt = 0; mt < 4; mt++)
#pragma unroll
                for (int nt = 0; nt < 4; nt++)
                    acc[mt][nt] = __builtin_amdgcn_mfma_f32_16x16x32_bf16(
                        af[mt], bfr[nt], acc[mt][nt], 0, 0, 0);
        }
        __syncthreads();
    }

    // ---- fused two-sided selection over two 128x64 half-tiles (fp32 stile) ----
    Top6 tkRow; top6_init(tkRow);
    const int srow = t >> 1, ss = t & 1;    // row-scan: 2 thr/row, 32 cols each
    const int scol = t >> 2, seg = t & 3;   // col-scan: 4 thr/col, interleaved rows

    for (int p = 0; p < 2; p++) {
        if (wc == p) {
#pragma unroll
            for (int mt = 0; mt < 4; mt++)
#pragma unroll
                for (int nt = 0; nt < 4; nt++)
#pragma unroll
                    for (int r = 0; r < 4; r++)
                        sm.sel.stile[(wr*64 + mt*16 + quad*4 + r) * 65 + nt*16 + col16] =
                            acc[mt][nt][r];
        }
        __syncthreads();
        // row side (persistent across halves); stride 65 -> conflict-free
#pragma unroll
        for (int c = 0; c < 32; c++) {
            float vv = sm.sel.stile[srow * 65 + ss*32 + c];
            top6_insert(tkRow, vv, colStart + p*64 + ss*32 + c);
        }
        // col side (per half)
        Top6 tkCol; top6_init(tkCol);
#pragma unroll
        for (int it = 0; it < 32; it++) {
            const int r = it*4 + seg;
            float vv = sm.sel.stile[r * 65 + scol];
            top6_insert(tkCol, vv, rowStart + r);
        }
#pragma unroll
        for (int m = 0; m < NSEL; m++) { sm.sel.pv[t*NSEL+m] = tkCol.v[m]; sm.sel.pi[t*NSEL+m] = tkCol.i[m]; }
        __syncthreads();
        if (bi != bj && t < 64) {
            Top6 mk; top6_init(mk);
            for (int s4 = 0; s4 < 4; s4++)
#pragma unroll
                for (int m2 = 0; m2 < NSEL; m2++)
                    top6_insert(mk, sm.sel.pv[(t*4+s4)*NSEL+m2], sm.sel.pi[(t*4+s4)*NSEL+m2]);
            const size_t base = (size_t)(colStart + p*64 + t) * NCAND + bi * NSEL;
#pragma unroll
            for (int m = 0; m < NSEL; m++) { cand_val[base+m] = mk.v[m]; cand_idx[base+m] = mk.i[m]; }
        }
        __syncthreads();
    }

    // row-side merge (2 partials per row)
#pragma unroll
    for (int m = 0; m < NSEL; m++) { sm.sel.pv[t*NSEL+m] = tkRow.v[m]; sm.sel.pi[t*NSEL+m] = tkRow.i[m]; }
    __syncthreads();
    if (t < 128) {
        Top6 mk; top6_init(mk);
        for (int s2 = 0; s2 < 2; s2++)
#pragma unroll
            for (int m2 = 0; m2 < NSEL; m2++)
                top6_insert(mk, sm.sel.pv[(t*2+s2)*NSEL+m2], sm.sel.pi[(t*2+s2)*NSEL+m2]);
        const size_t base = (size_t)(rowStart + t) * NCAND + bj * NSEL;
#pragma unroll
        for (int m = 0; m < NSEL; m++) { cand_val[base+m] = mk.v[m]; cand_idx[base+m] = mk.i[m]; }
    }
}

// ---------------------------------------------------------------------------
// Split-bf16 GEMM, BK=64 XOR-swizzled DMA (same layout rules as syrk).
// out[M,Nc] = (Ah+Al)@(Bh+Bl)^T + bias; tile 128x64, 4 waves (each 64x32).
// bias: col < SP ? bias0[col] : bias1[col-SP]  (U/V share one GEMM).
// ---------------------------------------------------------------------------
__global__ __launch_bounds__(256) void gemm_split(
    const unsigned short* __restrict__ Ah, const unsigned short* __restrict__ Al,
    const unsigned short* __restrict__ Bh, const unsigned short* __restrict__ Bl,
    const float* __restrict__ bias0, const float* __restrict__ bias1, int SP,
    float* __restrict__ out, int Nc)
{
    __shared__ unsigned short sAh[128*64], sAl[128*64], sBh[64*64], sBl[64*64]; // 48 KB
    const int t = threadIdx.x;
    const int lane = t & 63, w = t >> 6;
    const int wr = w >> 1, wc = w & 1;
    const int col16 = lane & 15, quad = lane >> 4;
    const int ln8 = lane >> 3;
    const int csw = ((lane & 7) ^ ln8) * 8;
    const int rowStart = blockIdx.y * 128, colStart = blockIdx.x * 64;

    f32x4 acc[4][2] = {};

    for (int k0 = 0; k0 < C_; k0 += 64) {
        // 48 DMA units of 1 KB (8 rows x 64 bf16): Ah 16, Al 16, Bh 8, Bl 8
#pragma unroll
        for (int j = 0; j < 12; j++) {
            const int u = w * 12 + j;
            const unsigned short* gs; unsigned short* ld;
            if (u < 16)      { const int rb = u*8;       gs = Ah + (size_t)(rowStart + rb + ln8) * C_; ld = sAh + rb*64; }
            else if (u < 32) { const int rb = (u-16)*8;  gs = Al + (size_t)(rowStart + rb + ln8) * C_; ld = sAl + rb*64; }
            else if (u < 40) { const int rb = (u-32)*8;  gs = Bh + (size_t)(colStart + rb + ln8) * C_; ld = sBh + rb*64; }
            else             { const int rb = (u-40)*8;  gs = Bl + (size_t)(colStart + rb + ln8) * C_; ld = sBl + rb*64; }
            dma16(gs + k0 + csw, ld);
        }
        __syncthreads();

#pragma unroll
        for (int ks = 0; ks < 2; ks++) {
            short8 ah[4], al4[4], bh2[2], bl2[2];
#pragma unroll
            for (int mt = 0; mt < 4; mt++) {
                const int r = wr*64 + mt*16 + col16;
                const int ro = r * 64 + (((ks*4 + quad) ^ (r & 7)) * 8);
                ah[mt]  = *(const short8*)&sAh[ro];
                al4[mt] = *(const short8*)&sAl[ro];
            }
#pragma unroll
            for (int nt = 0; nt < 2; nt++) {
                const int r = wc*32 + nt*16 + col16;
                const int ro = r * 64 + (((ks*4 + quad) ^ (r & 7)) * 8);
                bh2[nt] = *(const short8*)&sBh[ro];
                bl2[nt] = *(const short8*)&sBl[ro];
            }
#pragma unroll
            for (int mt = 0; mt < 4; mt++)
#pragma unroll
                for (int nt = 0; nt < 2; nt++) {
                    acc[mt][nt] = __builtin_amdgcn_mfma_f32_16x16x32_bf16(al4[mt], bh2[nt], acc[mt][nt], 0, 0, 0);
                    acc[mt][nt] = __builtin_amdgcn_mfma_f32_16x16x32_bf16(ah[mt],  bl2[nt], acc[mt][nt], 0, 0, 0);
                    acc[mt][nt] = __builtin_amdgcn_mfma_f32_16x16x32_bf16(ah[mt],  bh2[nt], acc[mt][nt], 0, 0, 0);
                }
        }
        __syncthreads();
    }

#pragma unroll
    for (int nt = 0; nt < 2; nt++) {
        const int col = colStart + wc*32 + nt*16 + col16;
        const float bns = (col < SP) ? bias0[col] : bias1[col - SP];
#pragma unroll
        for (int mt = 0; mt < 4; mt++)
#pragma unroll
            for (int r = 0; r < 4; r++) {
                const int row = rowStart + wr*64 + mt*16 + quad*4 + r;
                out[(size_t)row * Nc + col] = acc[mt][nt][r] + bns;
            }
    }
}

// ---------------------------------------------------------------------------
// Wave-parallel exact top-k (one wave/row): 16x butterfly argmax-extract over
// 192 candidates, fp64 re-check, 4th-largest threshold, neighbor write.
// ---------------------------------------------------------------------------
__global__ __launch_bounds__(256) void topk_merge(
    const float* __restrict__ x,
    const float* __restrict__ cand_val, const int* __restrict__ cand_idx,
    int* __restrict__ nbr_idx, int* __restrict__ nbr_cnt,
    float* __restrict__ dinv_arr)
{
    const int wv = threadIdx.x >> 6, lane = threadIdx.x & 63;
    const int row = blockIdx.x * 4 + wv;

    const size_t cb = (size_t)row * NCAND;
    float lv0 = cand_val[cb + lane];
    float lv1 = cand_val[cb + 64 + lane];
    float lv2 = cand_val[cb + 128 + lane];
    int   gi0 = cand_idx[cb + lane];
    int   gi1 = cand_idx[cb + 64 + lane];
    int   gi2 = cand_idx[cb + 128 + lane];

    int tj[NCHK];
#pragma unroll
    for (int it = 0; it < NCHK; it++) {
        float bv = lv0; int bm = gi0;
        if (lv1 > bv || (lv1 == bv && gi1 < bm)) { bv = lv1; bm = gi1; }
        if (lv2 > bv || (lv2 == bv && gi2 < bm)) { bv = lv2; bm = gi2; }
#pragma unroll
        for (int off = 32; off; off >>= 1) {
            float ov = __shfl_xor(bv, off);
            int   om = __shfl_xor(bm, off);
            if (ov > bv || (ov == bv && om < bm)) { bv = ov; bm = om; }
        }
        tj[it] = bm;
        if (bm == gi0)      lv0 = -1e30f;
        else if (bm == gi1) lv1 = -1e30f;
        else if (bm == gi2) lv2 = -1e30f;
    }

    const float* xr = x + (size_t)row * C_;
    float xrv[8];
#pragma unroll
    for (int k = 0; k < 8; k++) xrv[k] = xr[lane + k*64];

    double dvr[NCHK];
#pragma unroll
    for (int c = 0; c < NCHK; c++) {
        const float* xj = x + (size_t)tj[c] * C_;
        double s = 0.0;
#pragma unroll
        for (int k = 0; k < 8; k++)
            s += (double)xrv[k] * (double)xj[lane + k*64];
#pragma unroll
        for (int off = 32; off; off >>= 1) s += __shfl_xor(s, off);
        dvr[c] = s;
    }

    double m0 = -1e300, m1 = -1e300, m2 = -1e300, m3 = -1e300;
#pragma unroll
    for (int c = 0; c < NCHK; c++) {
        double v = dvr[c];
        if (v > m3) {
            if (v > m0)      { m3 = m2; m2 = m1; m1 = m0; m0 = v; }
            else if (v > m1) { m3 = m2; m2 = m1; m1 = v; }
            else if (v > m2) { m3 = m2; m2 = v; }
            else               m3 = v;
        }
    }
    const double thr = m3;

    if (lane == 0) {
        int cnt = 0;
#pragma unroll
        for (int c = 0; c < NCHK; c++) {
            bool keep = dvr[c] >= thr;
            if (keep) nbr_idx[(size_t)row * MAXN + cnt] = tj[c];
            cnt += keep ? 1 : 0;
        }
        nbr_cnt[row]  = cnt;
        dinv_arr[row] = (float)(1.0 / sqrt((double)cnt));
    }
}

// ---------------------------------------------------------------------------
// z = u + dinv_i * sum_j dinv_j * v_j ; per-row BN over C ; relu(x + norm).
// zuv[N][1024]: cols 0..511 = u-part, 512..1023 = v-part (fused U/V GEMM).
// Emits h split into bf16 hi/lo planes for the fc GEMM.
// ---------------------------------------------------------------------------
__global__ __launch_bounds__(256) void aggregate_bn(
    const float* __restrict__ x, const float* __restrict__ zuv,
    const int* __restrict__ nbr_idx, const int* __restrict__ nbr_cnt,
    const float* __restrict__ dinv_arr,
    unsigned short* __restrict__ hh, unsigned short* __restrict__ hl)
{
    const int row = blockIdx.x;
    const int t = threadIdx.x;
    __shared__ int   s_nbr[MAXN];
    __shared__ float s_w[MAXN];
    __shared__ int   s_cnt;
    __shared__ float s_di;
    __shared__ float r1[4], r2[4];
    __shared__ float s_mean, s_istd;

    if (t == 0) { s_cnt = nbr_cnt[row]; s_di = dinv_arr[row]; }
    __syncthreads();
    const int cnt = s_cnt;
    if (t < cnt) {
        int j = nbr_idx[(size_t)row * MAXN + t];
        s_nbr[t] = j;
        s_w[t]   = dinv_arr[j];
    }
    __syncthreads();

    const float di = s_di;
    float z[2];
    float sum = 0.f, sumsq = 0.f;
#pragma unroll
    for (int e = 0; e < 2; e++) {
        const int c = t + e * 256;
        float s = 0.f;
        for (int m = 0; m < cnt; m++)
            s += s_w[m] * zuv[(size_t)s_nbr[m] * 1024 + 512 + c];
        float zz = zuv[(size_t)row * 1024 + c] + di * s;
        z[e] = zz;
        sum += zz; sumsq += zz * zz;
    }

    float a = sum, b = sumsq;
#pragma unroll
    for (int o = 32; o > 0; o >>= 1) { a += __shfl_down(a, o); b += __shfl_down(b, o); }
    const int wave = t >> 6, lane = t & 63;
    if (lane == 0) { r1[wave] = a; r2[wave] = b; }
    __syncthreads();
    if (t == 0) {
        float ta = r1[0] + r1[1] + r1[2] + r1[3];
        float tb = r2[0] + r2[1] + r2[2] + r2[3];
        float mean = ta / (float)C_;
        float var  = tb / (float)C_ - mean * mean;
        s_mean = mean;
        s_istd = 1.0f / sqrtf(var + EPSF);
    }
    __syncthreads();

    const float mean = s_mean, istd = s_istd;
#pragma unroll
    for (int e = 0; e < 2; e++) {
        const int c = t + e * 256;
        float hhv = fmaxf(x[(size_t)row * C_ + c] + (z[e] - mean) * istd, 0.f);
        unsigned short hb = f2bf(hhv);
        hh[(size_t)row * C_ + c] = hb;
        hl[(size_t)row * C_ + c] = f2bf(hhv - bf2f(hb));
    }
}

// ---------------------------------------------------------------------------
extern "C" void kernel_launch(void* const* d_in, const int* in_sizes, int n_in,
                              void* d_out, int out_size, void* d_ws, size_t ws_size,
                              hipStream_t stream)
{
    const float* x    = (const float*)d_in[0];
    const float* U_w  = (const float*)d_in[1];
    const float* U_b  = (const float*)d_in[2];
    const float* V_w  = (const float*)d_in[3];
    const float* V_b  = (const float*)d_in[4];
    const float* fc_w = (const float*)d_in[5];
    const float* fc_b = (const float*)d_in[6];
    float* out = (float*)d_out;

    char* p = (char*)d_ws;
    auto alloc = [&](size_t bytes) { char* r = p; p += (bytes + 255) & ~(size_t)255; return r; };
    unsigned short* xh = (unsigned short*)alloc((size_t)N_ * C_ * 2);
    unsigned short* xl = (unsigned short*)alloc((size_t)N_ * C_ * 2);
    unsigned short* wh = (unsigned short*)alloc((size_t)1024 * C_ * 2);   // [U_w; V_w] hi
    unsigned short* wl = (unsigned short*)alloc((size_t)1024 * C_ * 2);   // [U_w; V_w] lo
    unsigned short* fh = (unsigned short*)alloc((size_t)OUT_ * C_ * 2);
    unsigned short* fl = (unsigned short*)alloc((size_t)OUT_ * C_ * 2);
    unsigned short* hh = (unsigned short*)alloc((size_t)N_ * C_ * 2);
    unsigned short* hl = (unsigned short*)alloc((size_t)N_ * C_ * 2);
    float* zuv      = (float*)alloc((size_t)N_ * 1024 * 4);               // u | v
    float* cand_val = (float*)alloc((size_t)N_ * NCAND * 4);
    int*   cand_idx = (int*)  alloc((size_t)N_ * NCAND * 4);
    int*   nbr_idx  = (int*)  alloc((size_t)N_ * MAXN * 4);
    int*   nbr_cnt  = (int*)  alloc((size_t)N_ * 4);
    float* dinv     = (float*)alloc((size_t)N_ * 4);

    // fp32 -> bf16 hi/lo planes
    hipLaunchKernelGGL(split_bf16_kernel, dim3(N_*C_/4/256), dim3(256), 0, stream, x, xh, xl, N_*C_/4);
    hipLaunchKernelGGL(split_bf16_kernel, dim3(C_*C_/4/256), dim3(256), 0, stream, U_w, wh, wl, C_*C_/4);
    hipLaunchKernelGGL(split_bf16_kernel, dim3(C_*C_/4/256), dim3(256), 0, stream, V_w, wh + (size_t)C_*C_, wl + (size_t)C_*C_, C_*C_/4);
    hipLaunchKernelGGL(split_bf16_kernel, dim3(OUT_*C_/4/256), dim3(256), 0, stream, fc_w, fh, fl, OUT_*C_/4);

    // similarity (triangle) + two-sided per-tile top-6 candidates
    hipLaunchKernelGGL(syrk_topk_mfma, dim3(NSTRIPE*(NSTRIPE+1)/2), dim3(256), 0, stream,
                       xh, cand_val, cand_idx);

    // exact merge -> neighbors, deg, dinv
    hipLaunchKernelGGL(topk_merge, dim3(N_/4), dim3(256), 0, stream,
                       x, cand_val, cand_idx, nbr_idx, nbr_cnt, dinv);

    // fused [u|v] = x @ [U_w;V_w]^T + [U_b|V_b]
    hipLaunchKernelGGL(gemm_split, dim3(1024/64, N_/128), dim3(256), 0, stream,
                       xh, xl, wh, wl, U_b, V_b, 512, zuv, 1024);

    // aggregate + BN + relu -> h (bf16 split)
    hipLaunchKernelGGL(aggregate_bn, dim3(N_), dim3(256), 0, stream,
                       x, zuv, nbr_idx, nbr_cnt, dinv, hh, hl);

    // out = h @ fc_w.T + fc_b
    hipLaunchKernelGGL(gemm_split, dim3(OUT_/64, N_/128), dim3(256), 0, stream,
                       hh, hl, fh, fl, fc_b, fc_b, 1 << 30, out, OUT_);
}

// Round 6
// 183.467 us; speedup vs baseline: 3.6068x; 1.3585x over previous
//
#include <hip/hip_runtime.h>
#include <cstddef>
#include <cstdint>

#define N_    4096
#define C_    512
#define OUT_  256
#define EPSF  1e-5f

#define NCHK   8              // global top-8 candidates, fp64 re-checked
#define MAXN   8              // max stored neighbors

typedef __attribute__((ext_vector_type(8))) short short8;
typedef __attribute__((ext_vector_type(4))) float f32x4;

typedef unsigned int u32;
typedef const u32 __attribute__((address_space(1)))* gptr_t;
typedef u32 __attribute__((address_space(3)))* lptr_t;

// Async global->LDS DMA, 16 B/lane. LDS dst = wave-uniform base + lane*16.
__device__ __forceinline__ void dma16(const unsigned short* g, unsigned short* l) {
    __builtin_amdgcn_global_load_lds((gptr_t)(uintptr_t)g, (lptr_t)(uintptr_t)l, 16, 0, 0);
}

__device__ __forceinline__ unsigned short f2bf(float f) {
    union { float f; unsigned u; } v; v.f = f;
    return (unsigned short)((v.u + 0x7FFFu + ((v.u >> 16) & 1u)) >> 16);
}
__device__ __forceinline__ float bf2f(unsigned short h) {
    union { unsigned u; float f; } v; v.u = ((unsigned)h) << 16;
    return v.f;
}

// Branchless constant-index top-8 insert (descending) — stays in VGPRs.
struct Top8 { float v[8]; int i[8]; };
__device__ __forceinline__ void top8_init(Top8& s) {
#pragma unroll
    for (int m = 0; m < 8; m++) { s.v[m] = -1e30f; s.i[m] = -1; }
}
__device__ __forceinline__ void top8_insert(Top8& s, float vv, int gc) {
    if (vv <= s.v[7]) return;
    bool g0 = vv > s.v[0], g1 = vv > s.v[1], g2 = vv > s.v[2], g3 = vv > s.v[3],
         g4 = vv > s.v[4], g5 = vv > s.v[5], g6 = vv > s.v[6];
    s.v[7] = g6 ? s.v[6] : vv;                  s.i[7] = g6 ? s.i[6] : gc;
    s.v[6] = g5 ? s.v[5] : (g6 ? vv : s.v[6]);  s.i[6] = g5 ? s.i[5] : (g6 ? gc : s.i[6]);
    s.v[5] = g4 ? s.v[4] : (g5 ? vv : s.v[5]);  s.i[5] = g4 ? s.i[4] : (g5 ? gc : s.i[5]);
    s.v[4] = g3 ? s.v[3] : (g4 ? vv : s.v[4]);  s.i[4] = g3 ? s.i[3] : (g4 ? gc : s.i[4]);
    s.v[3] = g2 ? s.v[2] : (g3 ? vv : s.v[3]);  s.i[3] = g2 ? s.i[2] : (g3 ? gc : s.i[3]);
    s.v[2] = g1 ? s.v[1] : (g2 ? vv : s.v[2]);  s.i[2] = g1 ? s.i[1] : (g2 ? gc : s.i[2]);
    s.v[1] = g0 ? s.v[0] : (g1 ? vv : s.v[1]);  s.i[1] = g0 ? s.i[0] : (g1 ? gc : s.i[1]);
    s.v[0] = g0 ? vv : s.v[0];                  s.i[0] = g0 ? gc : s.i[0];
}

// ---------------------------------------------------------------------------
// Split each fp32 into hi/lo bf16 planes: x ~= hi + lo.
// ---------------------------------------------------------------------------
__global__ __launch_bounds__(256) void split_bf16_kernel(
    const float* __restrict__ src, unsigned short* __restrict__ hi,
    unsigned short* __restrict__ lo, int n4)
{
    int i = blockIdx.x * 256 + threadIdx.x;
    if (i >= n4) return;
    float4 f = ((const float4*)src)[i];
    ushort4 h, l;
    h.x = f2bf(f.x); l.x = f2bf(f.x - bf2f(h.x));
    h.y = f2bf(f.y); l.y = f2bf(f.y - bf2f(h.y));
    h.z = f2bf(f.z); l.z = f2bf(f.z - bf2f(h.z));
    h.w = f2bf(f.w); l.w = f2bf(f.w - bf2f(h.w));
    ((ushort4*)hi)[i] = h;
    ((ushort4*)lo)[i] = l;
}

// ---------------------------------------------------------------------------
// Pure MFMA syrk GEMM: si[4096][4096] = bf16(xh @ xh^T). 128x128 tile/block,
// 32 KB LDS (5 blocks/CU), swizzled global_load_lds staging, no epilogue
// logic beyond the C-write. (Selection moved to rowsel.)
// ---------------------------------------------------------------------------
__global__ __launch_bounds__(256) void syrk_gemm(
    const unsigned short* __restrict__ xb, unsigned short* __restrict__ si)
{
    __shared__ unsigned short sA[128 * 64], sB[128 * 64];   // 32 KB
    const int t = threadIdx.x;
    const int lane = t & 63, w = t >> 6;
    const int wr = w >> 1, wc = w & 1;
    const int col16 = lane & 15, quad = lane >> 4;
    const int ln8 = lane >> 3;
    const int csw = ((lane & 7) ^ ln8) * 8;   // XOR-swizzled chunk (bank spread)

    const int rowStart = blockIdx.y * 128, colStart = blockIdx.x * 128;

    f32x4 acc[4][4] = {};

    for (int k0 = 0; k0 < C_; k0 += 64) {
#pragma unroll
        for (int i = 0; i < 4; i++) {
            const int r8 = w * 32 + i * 8;   // 8 rows per 1 KB DMA
            dma16(xb + (size_t)(rowStart + r8 + ln8) * C_ + k0 + csw, &sA[r8 * 64]);
            dma16(xb + (size_t)(colStart + r8 + ln8) * C_ + k0 + csw, &sB[r8 * 64]);
        }
        __syncthreads();
#pragma unroll
        for (int ks = 0; ks < 2; ks++) {
            short8 af[4], bfr[4];
#pragma unroll
            for (int mt = 0; mt < 4; mt++) {
                const int r = wr*64 + mt*16 + col16;
                af[mt] = *(const short8*)&sA[r * 64 + (((ks*4 + quad) ^ (r & 7)) * 8)];
            }
#pragma unroll
            for (int nt = 0; nt < 4; nt++) {
                const int r = wc*64 + nt*16 + col16;
                bfr[nt] = *(const short8*)&sB[r * 64 + (((ks*4 + quad) ^ (r & 7)) * 8)];
            }
#pragma unroll
            for (int mt = 0; mt < 4; mt++)
#pragma unroll
                for (int nt = 0; nt < 4; nt++)
                    acc[mt][nt] = __builtin_amdgcn_mfma_f32_16x16x32_bf16(
                        af[mt], bfr[nt], acc[mt][nt], 0, 0, 0);
        }
        __syncthreads();
    }

#pragma unroll
    for (int mt = 0; mt < 4; mt++)
#pragma unroll
        for (int r = 0; r < 4; r++) {
            const size_t rowOff = (size_t)(rowStart + wr*64 + mt*16 + quad*4 + r) * N_;
#pragma unroll
            for (int nt = 0; nt < 4; nt++)
                si[rowOff + colStart + wc*64 + nt*16 + col16] = f2bf(acc[mt][nt][r]);
        }
}

// ---------------------------------------------------------------------------
// Row selection + exact re-check, one wave per row (4 rows/block):
// stream the 8 KB bf16 si row coalesced (short8), register top-8 per lane,
// 6 butterfly merge rounds, lane-0 broadcast, fp64 re-check of the 8,
// 4th-largest threshold -> neighbors + dinv. No LDS, no barriers.
// ---------------------------------------------------------------------------
__global__ __launch_bounds__(256) void rowsel(
    const unsigned short* __restrict__ si, const float* __restrict__ x,
    int* __restrict__ nbr_idx, int* __restrict__ nbr_cnt,
    float* __restrict__ dinv_arr)
{
    const int wv = threadIdx.x >> 6, lane = threadIdx.x & 63;
    const int row = blockIdx.x * 4 + wv;

    Top8 s; top8_init(s);
    const unsigned short* sr = si + (size_t)row * N_;
#pragma unroll
    for (int it = 0; it < 8; it++) {
        short8 pack = *(const short8*)&sr[it * 512 + lane * 8];
#pragma unroll
        for (int e = 0; e < 8; e++)
            top8_insert(s, bf2f((unsigned short)pack[e]), it * 512 + lane * 8 + e);
    }

    // butterfly merge: after 6 rounds lane 0 holds a global top-8 (by value)
#pragma unroll
    for (int off = 1; off < 64; off <<= 1) {
        float pv[8]; int pi[8];
#pragma unroll
        for (int m = 0; m < 8; m++) {
            pv[m] = __shfl_xor(s.v[m], off);
            pi[m] = __shfl_xor(s.i[m], off);
        }
#pragma unroll
        for (int m = 0; m < 8; m++) top8_insert(s, pv[m], pi[m]);
    }

    int tj[NCHK];
#pragma unroll
    for (int c = 0; c < NCHK; c++) tj[c] = __shfl(s.i[c], 0);   // lane-0 set, consistent

    // fp64 exact dots for the 8 candidates
    const float* xr = x + (size_t)row * C_;
    float xrv[8];
#pragma unroll
    for (int k = 0; k < 8; k++) xrv[k] = xr[lane + k*64];

    double dvr[NCHK];
#pragma unroll
    for (int c = 0; c < NCHK; c++) {
        const float* xj = x + (size_t)tj[c] * C_;
        double sum = 0.0;
#pragma unroll
        for (int k = 0; k < 8; k++)
            sum += (double)xrv[k] * (double)xj[lane + k*64];
#pragma unroll
        for (int off = 32; off; off >>= 1) sum += __shfl_xor(sum, off);
        dvr[c] = sum;
    }

    // 4th largest of dvr[0..7]
    double m0 = -1e300, m1 = -1e300, m2 = -1e300, m3 = -1e300;
#pragma unroll
    for (int c = 0; c < NCHK; c++) {
        double v = dvr[c];
        if (v > m3) {
            if (v > m0)      { m3 = m2; m2 = m1; m1 = m0; m0 = v; }
            else if (v > m1) { m3 = m2; m2 = m1; m1 = v; }
            else if (v > m2) { m3 = m2; m2 = v; }
            else               m3 = v;
        }
    }
    const double thr = m3;

    if (lane == 0) {
        int cnt = 0;
#pragma unroll
        for (int c = 0; c < NCHK; c++) {
            bool keep = dvr[c] >= thr;
            if (keep) nbr_idx[(size_t)row * MAXN + cnt] = tj[c];
            cnt += keep ? 1 : 0;
        }
        nbr_cnt[row]  = cnt;
        dinv_arr[row] = (float)(1.0 / sqrt((double)cnt));
    }
}

// ---------------------------------------------------------------------------
// Split-bf16 GEMM, BK=64 XOR-swizzled DMA.
// out[M,Nc] = (Ah+Al)@(Bh+Bl)^T + bias; tile 128x64, 4 waves (each 64x32).
// bias: col < SP ? bias0[col] : bias1[col-SP]  (U/V share one GEMM).
// ---------------------------------------------------------------------------
__global__ __launch_bounds__(256) void gemm_split(
    const unsigned short* __restrict__ Ah, const unsigned short* __restrict__ Al,
    const unsigned short* __restrict__ Bh, const unsigned short* __restrict__ Bl,
    const float* __restrict__ bias0, const float* __restrict__ bias1, int SP,
    float* __restrict__ out, int Nc)
{
    __shared__ unsigned short sAh[128*64], sAl[128*64], sBh[64*64], sBl[64*64]; // 48 KB
    const int t = threadIdx.x;
    const int lane = t & 63, w = t >> 6;
    const int wr = w >> 1, wc = w & 1;
    const int col16 = lane & 15, quad = lane >> 4;
    const int ln8 = lane >> 3;
    const int csw = ((lane & 7) ^ ln8) * 8;
    const int rowStart = blockIdx.y * 128, colStart = blockIdx.x * 64;

    f32x4 acc[4][2] = {};

    for (int k0 = 0; k0 < C_; k0 += 64) {
#pragma unroll
        for (int j = 0; j < 12; j++) {
            const int u = w * 12 + j;
            const unsigned short* gs; unsigned short* ld;
            if (u < 16)      { const int rb = u*8;       gs = Ah + (size_t)(rowStart + rb + ln8) * C_; ld = sAh + rb*64; }
            else if (u < 32) { const int rb = (u-16)*8;  gs = Al + (size_t)(rowStart + rb + ln8) * C_; ld = sAl + rb*64; }
            else if (u < 40) { const int rb = (u-32)*8;  gs = Bh + (size_t)(colStart + rb + ln8) * C_; ld = sBh + rb*64; }
            else             { const int rb = (u-40)*8;  gs = Bl + (size_t)(colStart + rb + ln8) * C_; ld = sBl + rb*64; }
            dma16(gs + k0 + csw, ld);
        }
        __syncthreads();

#pragma unroll
        for (int ks = 0; ks < 2; ks++) {
            short8 ah[4], al4[4], bh2[2], bl2[2];
#pragma unroll
            for (int mt = 0; mt < 4; mt++) {
                const int r = wr*64 + mt*16 + col16;
                const int ro = r * 64 + (((ks*4 + quad) ^ (r & 7)) * 8);
                ah[mt]  = *(const short8*)&sAh[ro];
                al4[mt] = *(const short8*)&sAl[ro];
            }
#pragma unroll
            for (int nt = 0; nt < 2; nt++) {
                const int r = wc*32 + nt*16 + col16;
                const int ro = r * 64 + (((ks*4 + quad) ^ (r & 7)) * 8);
                bh2[nt] = *(const short8*)&sBh[ro];
                bl2[nt] = *(const short8*)&sBl[ro];
            }
#pragma unroll
            for (int mt = 0; mt < 4; mt++)
#pragma unroll
                for (int nt = 0; nt < 2; nt++) {
                    acc[mt][nt] = __builtin_amdgcn_mfma_f32_16x16x32_bf16(al4[mt], bh2[nt], acc[mt][nt], 0, 0, 0);
                    acc[mt][nt] = __builtin_amdgcn_mfma_f32_16x16x32_bf16(ah[mt],  bl2[nt], acc[mt][nt], 0, 0, 0);
                    acc[mt][nt] = __builtin_amdgcn_mfma_f32_16x16x32_bf16(ah[mt],  bh2[nt], acc[mt][nt], 0, 0, 0);
                }
        }
        __syncthreads();
    }

#pragma unroll
    for (int nt = 0; nt < 2; nt++) {
        const int col = colStart + wc*32 + nt*16 + col16;
        const float bns = (col < SP) ? bias0[col] : bias1[col - SP];
#pragma unroll
        for (int mt = 0; mt < 4; mt++)
#pragma unroll
            for (int r = 0; r < 4; r++) {
                const int row = rowStart + wr*64 + mt*16 + quad*4 + r;
                out[(size_t)row * Nc + col] = acc[mt][nt][r] + bns;
            }
    }
}

// ---------------------------------------------------------------------------
// z = u + dinv_i * sum_j dinv_j * v_j ; per-row BN over C ; relu(x + norm).
// zuv[N][1024]: cols 0..511 = u-part, 512..1023 = v-part (fused U/V GEMM).
// Emits h split into bf16 hi/lo planes for the fc GEMM.
// ---------------------------------------------------------------------------
__global__ __launch_bounds__(256) void aggregate_bn(
    const float* __restrict__ x, const float* __restrict__ zuv,
    const int* __restrict__ nbr_idx, const int* __restrict__ nbr_cnt,
    const float* __restrict__ dinv_arr,
    unsigned short* __restrict__ hh, unsigned short* __restrict__ hl)
{
    const int row = blockIdx.x;
    const int t = threadIdx.x;
    __shared__ int   s_nbr[MAXN];
    __shared__ float s_w[MAXN];
    __shared__ int   s_cnt;
    __shared__ float s_di;
    __shared__ float r1[4], r2[4];
    __shared__ float s_mean, s_istd;

    if (t == 0) { s_cnt = nbr_cnt[row]; s_di = dinv_arr[row]; }
    __syncthreads();
    const int cnt = s_cnt;
    if (t < cnt) {
        int j = nbr_idx[(size_t)row * MAXN + t];
        s_nbr[t] = j;
        s_w[t]   = dinv_arr[j];
    }
    __syncthreads();

    const float di = s_di;
    float z[2];
    float sum = 0.f, sumsq = 0.f;
#pragma unroll
    for (int e = 0; e < 2; e++) {
        const int c = t + e * 256;
        float sacc = 0.f;
        for (int m = 0; m < cnt; m++)
            sacc += s_w[m] * zuv[(size_t)s_nbr[m] * 1024 + 512 + c];
        float zz = zuv[(size_t)row * 1024 + c] + di * sacc;
        z[e] = zz;
        sum += zz; sumsq += zz * zz;
    }

    float a = sum, b = sumsq;
#pragma unroll
    for (int o = 32; o > 0; o >>= 1) { a += __shfl_down(a, o); b += __shfl_down(b, o); }
    const int wave = t >> 6, lane = t & 63;
    if (lane == 0) { r1[wave] = a; r2[wave] = b; }
    __syncthreads();
    if (t == 0) {
        float ta = r1[0] + r1[1] + r1[2] + r1[3];
        float tb = r2[0] + r2[1] + r2[2] + r2[3];
        float mean = ta / (float)C_;
        float var  = tb / (float)C_ - mean * mean;
        s_mean = mean;
        s_istd = 1.0f / sqrtf(var + EPSF);
    }
    __syncthreads();

    const float mean = s_mean, istd = s_istd;
#pragma unroll
    for (int e = 0; e < 2; e++) {
        const int c = t + e * 256;
        float hhv = fmaxf(x[(size_t)row * C_ + c] + (z[e] - mean) * istd, 0.f);
        unsigned short hb = f2bf(hhv);
        hh[(size_t)row * C_ + c] = hb;
        hl[(size_t)row * C_ + c] = f2bf(hhv - bf2f(hb));
    }
}

// ---------------------------------------------------------------------------
extern "C" void kernel_launch(void* const* d_in, const int* in_sizes, int n_in,
                              void* d_out, int out_size, void* d_ws, size_t ws_size,
                              hipStream_t stream)
{
    const float* x    = (const float*)d_in[0];
    const float* U_w  = (const float*)d_in[1];
    const float* U_b  = (const float*)d_in[2];
    const float* V_w  = (const float*)d_in[3];
    const float* V_b  = (const float*)d_in[4];
    const float* fc_w = (const float*)d_in[5];
    const float* fc_b = (const float*)d_in[6];
    float* out = (float*)d_out;

    char* p = (char*)d_ws;
    auto alloc = [&](size_t bytes) { char* r = p; p += (bytes + 255) & ~(size_t)255; return r; };
    unsigned short* si = (unsigned short*)alloc((size_t)N_ * N_ * 2);     // 32 MB bf16 similarity
    unsigned short* xh = (unsigned short*)alloc((size_t)N_ * C_ * 2);
    unsigned short* xl = (unsigned short*)alloc((size_t)N_ * C_ * 2);
    unsigned short* wh = (unsigned short*)alloc((size_t)1024 * C_ * 2);   // [U_w; V_w] hi
    unsigned short* wl = (unsigned short*)alloc((size_t)1024 * C_ * 2);   // [U_w; V_w] lo
    unsigned short* fh = (unsigned short*)alloc((size_t)OUT_ * C_ * 2);
    unsigned short* fl = (unsigned short*)alloc((size_t)OUT_ * C_ * 2);
    unsigned short* hh = (unsigned short*)alloc((size_t)N_ * C_ * 2);
    unsigned short* hl = (unsigned short*)alloc((size_t)N_ * C_ * 2);
    float* zuv      = (float*)alloc((size_t)N_ * 1024 * 4);               // u | v
    int*   nbr_idx  = (int*)  alloc((size_t)N_ * MAXN * 4);
    int*   nbr_cnt  = (int*)  alloc((size_t)N_ * 4);
    float* dinv     = (float*)alloc((size_t)N_ * 4);

    // fp32 -> bf16 hi/lo planes
    hipLaunchKernelGGL(split_bf16_kernel, dim3(N_*C_/4/256), dim3(256), 0, stream, x, xh, xl, N_*C_/4);
    hipLaunchKernelGGL(split_bf16_kernel, dim3(C_*C_/4/256), dim3(256), 0, stream, U_w, wh, wl, C_*C_/4);
    hipLaunchKernelGGL(split_bf16_kernel, dim3(C_*C_/4/256), dim3(256), 0, stream, V_w, wh + (size_t)C_*C_, wl + (size_t)C_*C_, C_*C_/4);
    hipLaunchKernelGGL(split_bf16_kernel, dim3(OUT_*C_/4/256), dim3(256), 0, stream, fc_w, fh, fl, OUT_*C_/4);

    // full similarity matrix (bf16), pure GEMM
    hipLaunchKernelGGL(syrk_gemm, dim3(N_/128, N_/128), dim3(256), 0, stream, xh, si);

    // per-row top-8 + fp64 re-check -> neighbors, deg, dinv
    hipLaunchKernelGGL(rowsel, dim3(N_/4), dim3(256), 0, stream,
                       si, x, nbr_idx, nbr_cnt, dinv);

    // fused [u|v] = x @ [U_w;V_w]^T + [U_b|V_b]
    hipLaunchKernelGGL(gemm_split, dim3(1024/64, N_/128), dim3(256), 0, stream,
                       xh, xl, wh, wl, U_b, V_b, 512, zuv, 1024);

    // aggregate + BN + relu -> h (bf16 split)
    hipLaunchKernelGGL(aggregate_bn, dim3(N_), dim3(256), 0, stream,
                       x, zuv, nbr_idx, nbr_cnt, dinv, hh, hl);

    // out = h @ fc_w.T + fc_b
    hipLaunchKernelGGL(gemm_split, dim3(OUT_/64, N_/128), dim3(256), 0, stream,
                       hh, hl, fh, fl, fc_b, fc_b, 1 << 30, out, OUT_);
}